// Round 4
// baseline (888.027 us; speedup 1.0000x reference)
//
#include <hip/hip_runtime.h>
#include <hip/hip_bf16.h>

typedef __bf16 bf16x8 __attribute__((ext_vector_type(8)));
typedef float f32x4 __attribute__((ext_vector_type(4)));

#define G_DIM 128

// ---- helpers ----
__device__ __forceinline__ float bf2f(ushort u) {
  return __uint_as_float(((unsigned int)u) << 16);
}

__device__ __forceinline__ bf16x8 cvt8(float4 f0, float4 f1) {
  bf16x8 v;
  v[0] = (__bf16)f0.x; v[1] = (__bf16)f0.y; v[2] = (__bf16)f0.z; v[3] = (__bf16)f0.w;
  v[4] = (__bf16)f1.x; v[5] = (__bf16)f1.y; v[6] = (__bf16)f1.z; v[7] = (__bf16)f1.w;
  return v;
}

// swizzled ushort index into a row-major [rows][128] bf16 LDS tile.
__device__ __forceinline__ int swz_idx(int row, int kc) {
  return (row * 128 + kc * 8) ^ ((row & 7) << 3);
}

// ---- W fp32 -> bf16 pre-conversion (5 matrices packed into one dst) ----
// layout (elem offsets): Wl@0, Wr@16384, W_ih@32768, W_hh@81920, Wfc@131072, total 147456
__global__ void k_wcvt(const float* __restrict__ Wl, const float* __restrict__ Wr,
                       const float* __restrict__ Wih, const float* __restrict__ Whh,
                       const float* __restrict__ Wfc, __bf16* __restrict__ dst) {
  int i = blockIdx.x * blockDim.x + threadIdx.x;
  if (i >= 147456 / 8) return;
  int e = i * 8;
  const float* src; int off;
  if (e < 16384)       { src = Wl;  off = e; }
  else if (e < 32768)  { src = Wr;  off = e - 16384; }
  else if (e < 81920)  { src = Wih; off = e - 32768; }
  else if (e < 131072) { src = Whh; off = e - 81920; }
  else                 { src = Wfc; off = e - 131072; }
  float4 a = ((const float4*)(src + off))[0];
  float4 b = ((const float4*)(src + off))[1];
  *(bf16x8*)(dst + e) = cvt8(a, b);
}

// ---- segment ranges from sorted batch ----
__global__ void k_seg(const int* __restrict__ batch, int* __restrict__ seg, int n, int g) {
  int i = blockIdx.x * blockDim.x + threadIdx.x;
  if (i >= n) return;
  int b = batch[i];
  int prev = (i == 0) ? -1 : batch[i - 1];
  for (int q = prev + 1; q <= b; ++q) seg[q] = i;
  if (i == n - 1) {
    for (int q = b + 1; q <= g; ++q) seg[q] = n;
  }
}

__global__ void k_zero4(float4* __restrict__ p, int n4) {
  int i = blockIdx.x * blockDim.x + threadIdx.x;
  if (i < n4) p[i] = float4{0.f, 0.f, 0.f, 0.f};
}

__global__ void k_relu4(float4* __restrict__ p, int n4) {
  int i = blockIdx.x * blockDim.x + threadIdx.x;
  if (i < n4) {
    float4 v = p[i];
    v.x = fmaxf(v.x, 0.f); v.y = fmaxf(v.y, 0.f);
    v.z = fmaxf(v.z, 0.f); v.w = fmaxf(v.w, 0.f);
    p[i] = v;
  }
}

// ---- big fused kernel: xl = bf16(x @ Wl.T + bl)  AND  pool += segment partial sums ----
// Batched in-stage loads (no cross-tile prefetch, no lambda -> no spill).
// Wave-local LDS-bounce epilogue: coalesced dwordx4 xl stores. 2 barriers/tile.
__global__ __launch_bounds__(256, 3) void k_xlgemm(const __bf16* __restrict__ Wbf,
                                                   const float* __restrict__ x,
                                                   const float* __restrict__ bias,
                                                   const int* __restrict__ batch,
                                                   __bf16* __restrict__ xl,
                                                   float* __restrict__ pool,
                                                   int rows, int ntiles) {
  __shared__ __align__(16) ushort sB[128 * 128];  // W, swizzled, persistent
  __shared__ __align__(16) ushort sA[64 * 128];   // x tile (swz) -> reused as xl tile (linear)
  __shared__ int sBatch[64];
  const int tid = threadIdx.x;
  const int lane = tid & 63;
  const int wv = tid >> 6;
  const int l15 = lane & 15;
  const int kg = lane >> 4;

  // stage W (bf16, already converted) once per block
  for (int c = tid; c < 128 * 16; c += 256) {
    int row = c >> 4, kc = c & 15;
    *(bf16x8*)(&sB[swz_idx(row, kc)]) = *(const bf16x8*)(Wbf + (long)row * 128 + kc * 8);
  }

  // per-block constant bias values for this thread's 8 output columns
  float bv[8];
  #pragma unroll
  for (int nt = 0; nt < 8; ++nt) bv[nt] = bias[nt * 16 + l15];

  const float4 z4 = float4{0.f, 0.f, 0.f, 0.f};

  for (int tile = blockIdx.x; tile < ntiles; tile += gridDim.x) {
    const long row0 = (long)tile * 64;
    // ---- stage: issue all 8 loads, then convert+write ----
    const int r0 = tid >> 4, kc0 = tid & 15;           // q=0 coords; q adds 16 rows
    float4 p0, p1, p2, p3, p4, p5, p6, p7;
    {
      const float4* s0 = (const float4*)(x + (row0 + r0) * 128 + kc0 * 8);
      const float4* s1 = (const float4*)(x + (row0 + r0 + 16) * 128 + kc0 * 8);
      const float4* s2 = (const float4*)(x + (row0 + r0 + 32) * 128 + kc0 * 8);
      const float4* s3 = (const float4*)(x + (row0 + r0 + 48) * 128 + kc0 * 8);
      bool v0 = row0 + r0 < rows, v1 = row0 + r0 + 16 < rows;
      bool v2 = row0 + r0 + 32 < rows, v3 = row0 + r0 + 48 < rows;
      p0 = v0 ? s0[0] : z4; p1 = v0 ? s0[1] : z4;
      p2 = v1 ? s1[0] : z4; p3 = v1 ? s1[1] : z4;
      p4 = v2 ? s2[0] : z4; p5 = v2 ? s2[1] : z4;
      p6 = v3 ? s3[0] : z4; p7 = v3 ? s3[1] : z4;
    }
    int breg = -1;
    if (tid < 64) {
      long gr = row0 + tid;
      breg = (gr < rows) ? batch[gr] : -1;
    }
    *(bf16x8*)(&sA[swz_idx(r0, kc0)]) = cvt8(p0, p1);
    *(bf16x8*)(&sA[swz_idx(r0 + 16, kc0)]) = cvt8(p2, p3);
    *(bf16x8*)(&sA[swz_idx(r0 + 32, kc0)]) = cvt8(p4, p5);
    *(bf16x8*)(&sA[swz_idx(r0 + 48, kc0)]) = cvt8(p6, p7);
    if (tid < 64) sBatch[tid] = breg;
    __syncthreads();

    // ---- MFMA: wave's 16-row band x 128 cols (all reads within own band + sB) ----
    f32x4 acc[8];
    #pragma unroll
    for (int nt = 0; nt < 8; ++nt) acc[nt] = f32x4{0.f, 0.f, 0.f, 0.f};
    const int mrow = wv * 16 + l15;
    #pragma unroll
    for (int ks = 0; ks < 4; ++ks) {
      bf16x8 af = *(const bf16x8*)(&sA[swz_idx(mrow, ks * 4 + kg)]);
      #pragma unroll
      for (int nt = 0; nt < 8; ++nt) {
        bf16x8 bfr = *(const bf16x8*)(&sB[swz_idx(nt * 16 + l15, ks * 4 + kg)]);
        acc[nt] = __builtin_amdgcn_mfma_f32_16x16x32_bf16(af, bfr, acc[nt], 0, 0, 0);
      }
    }

    // ---- pool: wave's own band, vectorized reads + shfl reduce (reads sA BEFORE epilogue overwrite) ----
    {
      int rbase = wv * 16;
      int bfirst = sBatch[rbase], blast = sBatch[rbase + 15];
      if (bfirst == blast) {
        if (bfirst >= 0) {  // fast path: whole slice one segment
          float s8[8];
          #pragma unroll
          for (int q = 0; q < 8; ++q) s8[q] = 0.f;
          #pragma unroll
          for (int j = 0; j < 4; ++j) {
            int row = rbase + kg + j * 4;
            bf16x8 v = *(const bf16x8*)(&sA[swz_idx(row, l15)]);
            #pragma unroll
            for (int q = 0; q < 8; ++q) s8[q] += (float)v[q];
          }
          #pragma unroll
          for (int q = 0; q < 8; ++q) {
            s8[q] += __shfl_xor(s8[q], 16, 64);
            s8[q] += __shfl_xor(s8[q], 32, 64);
          }
          if (kg == 0) {
            float* dst = pool + (long)bfirst * 128 + l15 * 8;
            #pragma unroll
            for (int q = 0; q < 8; ++q) atomicAdd(dst + q, s8[q]);
          }
        }
      } else {  // slow path: segment boundary inside slice
        float s8[8];
        #pragma unroll
        for (int q = 0; q < 8; ++q) s8[q] = 0.f;
        int cb = -1;
        #pragma unroll
        for (int j = 0; j < 4; ++j) {
          int row = rbase + kg + j * 4;
          int b = sBatch[row];
          if (b != cb) {
            if (cb >= 0) {
              float* dst = pool + (long)cb * 128 + l15 * 8;
              #pragma unroll
              for (int q = 0; q < 8; ++q) atomicAdd(dst + q, s8[q]);
            }
            #pragma unroll
            for (int q = 0; q < 8; ++q) s8[q] = 0.f;
            cb = b;
          }
          if (b >= 0) {
            bf16x8 v = *(const bf16x8*)(&sA[swz_idx(row, l15)]);
            #pragma unroll
            for (int q = 0; q < 8; ++q) s8[q] += (float)v[q];
          }
        }
        if (cb >= 0) {
          float* dst = pool + (long)cb * 128 + l15 * 8;
          #pragma unroll
          for (int q = 0; q < 8; ++q) atomicAdd(dst + q, s8[q]);
        }
      }
    }

    // ---- epilogue: overwrite own band of sA with linear bf16 results ----
    #pragma unroll
    for (int nt = 0; nt < 8; ++nt) {
      int col = nt * 16 + l15;
      #pragma unroll
      for (int j = 0; j < 4; ++j) {
        int brow = wv * 16 + kg * 4 + j;
        __bf16 hb = (__bf16)(acc[nt][j] + bv[nt]);
        sA[brow * 128 + col] = __builtin_bit_cast(ushort, hb);
      }
    }
    // ---- coalesced xl stores from own band (wave-local; no barrier needed) ----
    #pragma unroll
    for (int t = 0; t < 4; ++t) {
      int g = t * 64 + lane;
      int brow = g >> 4, chunk = g & 15;
      long grow = row0 + wv * 16 + brow;
      if (grow < rows) {
        bf16x8 v = *(const bf16x8*)(&sA[(wv * 16 + brow) * 128 + chunk * 8]);
        *(bf16x8*)(xl + grow * 128 + chunk * 8) = v;
      }
    }
    __syncthreads();
  }
}

// ---- small GEMM: out[r, c] = bias[c] + sum_k A[r,k] * W[c,k], W pre-converted bf16 ----
__global__ __launch_bounds__(256) void k_gemm128(const float* __restrict__ A,
                                                 const __bf16* __restrict__ W,
                                                 const float* __restrict__ bias,
                                                 float* __restrict__ out,
                                                 int rows) {
  __shared__ __align__(16) ushort sB[128 * 128];
  __shared__ __align__(16) ushort sA[64 * 128];
  const int tid = threadIdx.x;
  const long row0 = (long)blockIdx.x * 64;
  for (int c = tid; c < 128 * 16; c += 256) {
    int row = c >> 4, kc = c & 15;
    *(bf16x8*)(&sB[swz_idx(row, kc)]) = *(const bf16x8*)(W + (long)row * 128 + kc * 8);
  }
  for (int c = tid; c < 64 * 16; c += 256) {
    int r = c >> 4, kc = c & 15;
    long gr = row0 + r;
    bf16x8 v;
    if (gr < rows) {
      const float4* src = (const float4*)(A + gr * 128 + kc * 8);
      v = cvt8(src[0], src[1]);
    } else {
      #pragma unroll
      for (int q = 0; q < 8; ++q) v[q] = (__bf16)0.f;
    }
    *(bf16x8*)(&sA[swz_idx(r, kc)]) = v;
  }
  const int lane = tid & 63;
  const int wv = tid >> 6;
  const int l15 = lane & 15;
  const int kg = lane >> 4;
  __syncthreads();

  f32x4 acc[8];
  #pragma unroll
  for (int nt = 0; nt < 8; ++nt) acc[nt] = f32x4{0.f, 0.f, 0.f, 0.f};
  const int mrow = wv * 16 + l15;
  #pragma unroll
  for (int ks = 0; ks < 4; ++ks) {
    bf16x8 af = *(const bf16x8*)(&sA[swz_idx(mrow, ks * 4 + kg)]);
    #pragma unroll
    for (int nt = 0; nt < 8; ++nt) {
      bf16x8 bfr = *(const bf16x8*)(&sB[swz_idx(nt * 16 + l15, ks * 4 + kg)]);
      acc[nt] = __builtin_amdgcn_mfma_f32_16x16x32_bf16(af, bfr, acc[nt], 0, 0, 0);
    }
  }
  #pragma unroll
  for (int nt = 0; nt < 8; ++nt) {
    int col = nt * 16 + l15;
    float bvv = bias[col];
    #pragma unroll
    for (int j = 0; j < 4; ++j) {
      long r = row0 + wv * 16 + kg * 4 + j;
      if (r < rows) out[r * 128 + col] = acc[nt][j] + bvv;
    }
  }
}

// ---- fused GATv2: 4 rows per iteration, 16-lane groups, online softmax ----
__global__ __launch_bounds__(256) void k_gat(const __bf16* __restrict__ xl,
                                             const float* __restrict__ xr,
                                             const int* __restrict__ seg,
                                             const float* __restrict__ att,
                                             const float* __restrict__ gat_bias,
                                             float* __restrict__ h, int G) {
  int wid = (blockIdx.x << 2) + (threadIdx.x >> 6);
  if (wid >= G) return;
  int lane = threadIdx.x & 63;
  int grp = lane >> 4, li = lane & 15;
  int s = seg[wid], e = seg[wid + 1];
  int d0 = li * 8;

  const float* xrp = xr + (long)wid * G_DIM + d0;
  float xrv[8], atv[8];
  {
    float4 a0 = *(const float4*)(xrp);
    float4 a1 = *(const float4*)(xrp + 4);
    float4 t0 = *(const float4*)(att + d0);
    float4 t1 = *(const float4*)(att + d0 + 4);
    xrv[0]=a0.x; xrv[1]=a0.y; xrv[2]=a0.z; xrv[3]=a0.w;
    xrv[4]=a1.x; xrv[5]=a1.y; xrv[6]=a1.z; xrv[7]=a1.w;
    atv[0]=t0.x; atv[1]=t0.y; atv[2]=t0.z; atv[3]=t0.w;
    atv[4]=t1.x; atv[5]=t1.y; atv[6]=t1.z; atv[7]=t1.w;
  }

  float m = -1e30f, den = 0.f;
  float acc[8];
  #pragma unroll
  for (int q = 0; q < 8; ++q) acc[q] = 0.f;

  for (int base = s; base < e; base += 4) {
    int i = base + grp;
    bool valid = i < e;
    float xv[8];
    if (valid) {
      bf16x8 v = *(const bf16x8*)((const ushort*)xl + (long)i * G_DIM + d0);
      #pragma unroll
      for (int q = 0; q < 8; ++q) xv[q] = (float)v[q];
    } else {
      #pragma unroll
      for (int q = 0; q < 8; ++q) xv[q] = 0.f;
    }
    float p = 0.f;
    #pragma unroll
    for (int q = 0; q < 8; ++q) {
      float t = xv[q] + xrv[q];
      t = fmaxf(t, 0.f) + 0.01f * fminf(t, 0.f);
      p = fmaf(t, atv[q], p);
    }
    p += __shfl_xor(p, 1, 64);
    p += __shfl_xor(p, 2, 64);
    p += __shfl_xor(p, 4, 64);
    p += __shfl_xor(p, 8, 64);
    float pe = valid ? p : -1e30f;
    float e1 = __shfl_xor(pe, 16, 64);
    float e2 = __shfl_xor(pe, 32, 64);
    float e3 = __shfl_xor(e1, 32, 64);
    float nm = fmaxf(m, fmaxf(fmaxf(pe, e1), fmaxf(e2, e3)));
    float sc = __expf(m - nm);
    float w0 = __expf(pe - nm);
    den = den * sc + w0 + __expf(e1 - nm) + __expf(e2 - nm) + __expf(e3 - nm);
    #pragma unroll
    for (int q = 0; q < 8; ++q) acc[q] = acc[q] * sc + w0 * xv[q];
    m = nm;
  }
  #pragma unroll
  for (int q = 0; q < 8; ++q) {
    acc[q] += __shfl_xor(acc[q], 16, 64);
    acc[q] += __shfl_xor(acc[q], 32, 64);
  }
  if (grp == 0) {
    float inv = (e > s) ? 1.f / den : 0.f;
    float o[8];
    #pragma unroll
    for (int q = 0; q < 8; ++q) {
      float v = acc[q] * inv + gat_bias[d0 + q];
      o[q] = v > 0.f ? v : __expf(v) - 1.f;  // elu
    }
    float* dst = h + (long)wid * G_DIM + d0;
    *(float4*)(dst) = float4{o[0], o[1], o[2], o[3]};
    *(float4*)(dst + 4) = float4{o[4], o[5], o[6], o[7]};
  }
}

// ---- fused GRU: gi=h@W_ih.T, gh=cur@W_hh.T (bf16 W), gate math, relu -> nxt ----
__global__ __launch_bounds__(256) void k_grublock(const float* __restrict__ h,
                                                  const float* __restrict__ cur,
                                                  const __bf16* __restrict__ W_ih,
                                                  const __bf16* __restrict__ W_hh,
                                                  const float* __restrict__ b_ih,
                                                  const float* __restrict__ b_hh,
                                                  float* __restrict__ nxt, int G) {
  __shared__ __align__(16) ushort sA1[64 * 128];  // h tile
  __shared__ __align__(16) ushort sA2[64 * 128];  // cur tile
  __shared__ __align__(16) ushort sW[128 * 128];  // one gate of one W at a time
  const int tid = threadIdx.x;
  const int lane = tid & 63, wv = tid >> 6, l15 = lane & 15, kg = lane >> 4;
  const long row0 = (long)blockIdx.x * 64;
  const int mrow = wv * 16 + l15;

  for (int c = tid; c < 64 * 16; c += 256) {
    int r = c >> 4, kc = c & 15;
    long gr = row0 + r;
    const float4* s1 = (const float4*)(h + gr * 128 + kc * 8);
    const float4* s2 = (const float4*)(cur + gr * 128 + kc * 8);
    *(bf16x8*)(&sA1[swz_idx(r, kc)]) = cvt8(s1[0], s1[1]);
    *(bf16x8*)(&sA2[swz_idx(r, kc)]) = cvt8(s2[0], s2[1]);
  }

  f32x4 rp[8], zp[8], inn[8], hnn[8];
  #pragma unroll
  for (int nt = 0; nt < 8; ++nt) {
    rp[nt] = f32x4{0.f, 0.f, 0.f, 0.f};
    zp[nt] = f32x4{0.f, 0.f, 0.f, 0.f};
    inn[nt] = f32x4{0.f, 0.f, 0.f, 0.f};
    hnn[nt] = f32x4{0.f, 0.f, 0.f, 0.f};
  }

#define STAGE_W(WSRC, gate)                                                   \
  __syncthreads();                                                            \
  for (int c = tid; c < 128 * 16; c += 256) {                                 \
    int r = c >> 4, kc = c & 15;                                              \
    *(bf16x8*)(&sW[swz_idx(r, kc)]) =                                         \
        *(const bf16x8*)((WSRC) + ((long)(gate)*128 + r) * 128 + kc * 8);     \
  }                                                                           \
  __syncthreads();

#define MM(ACC, SAX)                                                          \
  _Pragma("unroll") for (int ks = 0; ks < 4; ++ks) {                          \
    bf16x8 af = *(const bf16x8*)(&SAX[swz_idx(mrow, ks * 4 + kg)]);           \
    _Pragma("unroll") for (int nt = 0; nt < 8; ++nt) {                        \
      bf16x8 bfr = *(const bf16x8*)(&sW[swz_idx(nt * 16 + l15, ks * 4 + kg)]);\
      ACC[nt] = __builtin_amdgcn_mfma_f32_16x16x32_bf16(af, bfr, ACC[nt], 0, 0, 0); \
    }                                                                         \
  }

  STAGE_W(W_ih, 0) MM(rp, sA1)
  STAGE_W(W_hh, 0) MM(rp, sA2)
  STAGE_W(W_ih, 1) MM(zp, sA1)
  STAGE_W(W_hh, 1) MM(zp, sA2)
  STAGE_W(W_ih, 2) MM(inn, sA1)
  STAGE_W(W_hh, 2) MM(hnn, sA2)
#undef STAGE_W
#undef MM

  #pragma unroll
  for (int nt = 0; nt < 8; ++nt) {
    int col = nt * 16 + l15;
    float bir = b_ih[col], biz = b_ih[col + 128], bin = b_ih[col + 256];
    float bhr = b_hh[col], bhz = b_hh[col + 128], bhn = b_hh[col + 256];
    #pragma unroll
    for (int j = 0; j < 4; ++j) {
      long r = row0 + wv * 16 + kg * 4 + j;
      if (r >= G) continue;
      float pre_r = rp[nt][j] + bir + bhr;
      float pre_z = zp[nt][j] + biz + bhz;
      float rr = 1.f / (1.f + __expf(-pre_r));
      float zz = 1.f / (1.f + __expf(-pre_z));
      float nn = tanhf(inn[nt][j] + bin + rr * (hnn[nt][j] + bhn));
      float hp = cur[r * 128 + col];
      nxt[r * 128 + col] = fmaxf((1.f - zz) * nn + zz * hp, 0.f);
    }
  }
}

extern "C" void kernel_launch(void* const* d_in, const int* in_sizes, int n_in,
                              void* d_out, int out_size, void* d_ws, size_t ws_size,
                              hipStream_t stream) {
  const float* x        = (const float*)d_in[0];
  const int*   batch    = (const int*)d_in[1];
  const float* Wl       = (const float*)d_in[2];
  const float* bl       = (const float*)d_in[3];
  const float* Wr       = (const float*)d_in[4];
  const float* br       = (const float*)d_in[5];
  const float* att      = (const float*)d_in[6];
  const float* gat_bias = (const float*)d_in[7];
  const float* W_ih     = (const float*)d_in[8];
  const float* W_hh     = (const float*)d_in[9];
  const float* b_ih     = (const float*)d_in[10];
  const float* b_hh     = (const float*)d_in[11];
  const float* Wfc      = (const float*)d_in[12];
  const float* bfc      = (const float*)d_in[13];
  const int N = in_sizes[1];
  const int G = out_size / G_DIM;
  float* outf = (float*)d_out;

  char* ws = (char*)d_ws;
  size_t off = 0;
  auto alloc = [&](size_t bytes) -> void* {
    void* p = ws + off;
    off = (off + bytes + 255) & ~(size_t)255;
    return p;
  };
  int*    seg   = (int*)alloc(((size_t)G + 1) * sizeof(int));
  float*  out_a = (float*)alloc((size_t)G * G_DIM * sizeof(float));
  float*  out_b = (float*)alloc((size_t)G * G_DIM * sizeof(float));
  float*  xr    = (float*)alloc((size_t)G * G_DIM * sizeof(float));
  float*  hbuf  = (float*)alloc((size_t)G * G_DIM * sizeof(float));
  __bf16* wsW   = (__bf16*)alloc((size_t)147456 * sizeof(ushort));
  __bf16* xl    = (__bf16*)alloc((size_t)N * G_DIM * sizeof(ushort));
  (void)ws_size; (void)n_in;

  __bf16* Wlb  = wsW;
  __bf16* Wrb  = wsW + 16384;
  __bf16* Wihb = wsW + 32768;
  __bf16* Whhb = wsW + 81920;
  __bf16* Wfcb = wsW + 131072;

  const int pool4 = G * G_DIM / 4;

  k_wcvt<<<(147456 / 8 + 255) / 256, 256, 0, stream>>>(Wl, Wr, W_ih, W_hh, Wfc, wsW);
  k_seg<<<(N + 255) / 256, 256, 0, stream>>>(batch, seg, N, G);
  k_zero4<<<(pool4 + 255) / 256, 256, 0, stream>>>((float4*)out_a, pool4);

  const int ntiles_big = (N + 63) / 64;
  k_xlgemm<<<768, 256, 0, stream>>>(Wlb, x, bl, batch, xl, out_a, N, ntiles_big);
  k_relu4<<<(pool4 + 255) / 256, 256, 0, stream>>>((float4*)out_a, pool4);

  const int ntiles_g = (G + 63) / 64;
  const float* cur = out_a;
  float* nxt = out_b;
  for (int t = 0; t < 3; ++t) {
    k_gemm128<<<ntiles_g, 256, 0, stream>>>(cur, Wrb, br, xr, G);
    k_gat<<<(G + 3) / 4, 256, 0, stream>>>(xl, xr, seg, att, gat_bias, hbuf, G);
    k_grublock<<<ntiles_g, 256, 0, stream>>>(hbuf, cur, Wihb, Whhb, b_ih, b_hh, nxt, G);
    const float* tmp = cur;
    cur = nxt;
    nxt = (float*)tmp;
  }
  k_gemm128<<<ntiles_g, 256, 0, stream>>>(cur, Wfcb, bfc, outf, G);
}

// Round 5
// 349.758 us; speedup vs baseline: 2.5390x; 2.5390x over previous
//
#include <hip/hip_runtime.h>
#include <hip/hip_bf16.h>

typedef __bf16 bf16x8 __attribute__((ext_vector_type(8)));
typedef float f32x4 __attribute__((ext_vector_type(4)));

#define G_DIM 128

// ---- helpers ----
__device__ __forceinline__ float bf2f(ushort u) {
  return __uint_as_float(((unsigned int)u) << 16);
}

__device__ __forceinline__ bf16x8 cvt8(float4 f0, float4 f1) {
  bf16x8 v;
  v[0] = (__bf16)f0.x; v[1] = (__bf16)f0.y; v[2] = (__bf16)f0.z; v[3] = (__bf16)f0.w;
  v[4] = (__bf16)f1.x; v[5] = (__bf16)f1.y; v[6] = (__bf16)f1.z; v[7] = (__bf16)f1.w;
  return v;
}

// swizzled ushort index into a row-major [rows][128] bf16 LDS tile.
__device__ __forceinline__ int swz_idx(int row, int kc) {
  return (row * 128 + kc * 8) ^ ((row & 7) << 3);
}

// ---- W fp32 -> bf16 pre-conversion (5 matrices packed into one dst) ----
// layout (elem offsets): Wl@0, Wr@16384, W_ih@32768, W_hh@81920, Wfc@131072, total 147456
__global__ void k_wcvt(const float* __restrict__ Wl, const float* __restrict__ Wr,
                       const float* __restrict__ Wih, const float* __restrict__ Whh,
                       const float* __restrict__ Wfc, __bf16* __restrict__ dst) {
  int i = blockIdx.x * blockDim.x + threadIdx.x;
  if (i >= 147456 / 8) return;
  int e = i * 8;
  const float* src; int off;
  if (e < 16384)       { src = Wl;  off = e; }
  else if (e < 32768)  { src = Wr;  off = e - 16384; }
  else if (e < 81920)  { src = Wih; off = e - 32768; }
  else if (e < 131072) { src = Whh; off = e - 81920; }
  else                 { src = Wfc; off = e - 131072; }
  float4 a = ((const float4*)(src + off))[0];
  float4 b = ((const float4*)(src + off))[1];
  *(bf16x8*)(dst + e) = cvt8(a, b);
}

// ---- segment ranges from sorted batch ----
__global__ void k_seg(const int* __restrict__ batch, int* __restrict__ seg, int n, int g) {
  int i = blockIdx.x * blockDim.x + threadIdx.x;
  if (i >= n) return;
  int b = batch[i];
  int prev = (i == 0) ? -1 : batch[i - 1];
  for (int q = prev + 1; q <= b; ++q) seg[q] = i;
  if (i == n - 1) {
    for (int q = b + 1; q <= g; ++q) seg[q] = n;
  }
}

// ---- pool: out0 = relu(segment_sum(x)). One wave per graph: NO atomics. ----
__global__ __launch_bounds__(256) void k_pool(const float* __restrict__ x,
                                              const int* __restrict__ seg,
                                              float* __restrict__ out0, int G) {
  int wid = (blockIdx.x << 2) + (threadIdx.x >> 6);
  if (wid >= G) return;
  int lane = threadIdx.x & 63;
  int grp = lane >> 4, li = lane & 15;
  int s = seg[wid], e = seg[wid + 1];
  float acc[8];
  #pragma unroll
  for (int q = 0; q < 8; ++q) acc[q] = 0.f;
  for (int base = s; base < e; base += 4) {
    int i = base + grp;
    if (i < e) {
      const float4* src = (const float4*)(x + (long)i * G_DIM + li * 8);
      float4 u = src[0], v = src[1];
      acc[0] += u.x; acc[1] += u.y; acc[2] += u.z; acc[3] += u.w;
      acc[4] += v.x; acc[5] += v.y; acc[6] += v.z; acc[7] += v.w;
    }
  }
  #pragma unroll
  for (int q = 0; q < 8; ++q) {
    acc[q] += __shfl_xor(acc[q], 16, 64);
    acc[q] += __shfl_xor(acc[q], 32, 64);
  }
  if (grp == 0) {
    float* dst = out0 + (long)wid * G_DIM + li * 8;
    *(float4*)(dst) = float4{fmaxf(acc[0], 0.f), fmaxf(acc[1], 0.f),
                             fmaxf(acc[2], 0.f), fmaxf(acc[3], 0.f)};
    *(float4*)(dst + 4) = float4{fmaxf(acc[4], 0.f), fmaxf(acc[5], 0.f),
                                 fmaxf(acc[6], 0.f), fmaxf(acc[7], 0.f)};
  }
}

// ---- pure GEMM: xl = bf16(x @ Wl.T + bl). Register prefetch + LDS-bounce epilogue. ----
__global__ __launch_bounds__(256, 3) void k_xlgemm(const __bf16* __restrict__ Wbf,
                                                   const float* __restrict__ x,
                                                   const float* __restrict__ bias,
                                                   __bf16* __restrict__ xl,
                                                   int rows, int ntiles) {
  __shared__ __align__(16) ushort sB[128 * 128];  // W, swizzled, persistent
  __shared__ __align__(16) ushort sA[64 * 128];   // x tile (swz) -> reused as xl tile (linear)
  const int tid = threadIdx.x;
  const int lane = tid & 63;
  const int wv = tid >> 6;
  const int l15 = lane & 15;
  const int kg = lane >> 4;
  const int r0 = tid >> 4, kc0 = tid & 15;
  const float4 z4 = float4{0.f, 0.f, 0.f, 0.f};

  // stage W (bf16, already converted) once per block
  for (int c = tid; c < 128 * 16; c += 256) {
    int row = c >> 4, kc = c & 15;
    *(bf16x8*)(&sB[swz_idx(row, kc)]) = *(const bf16x8*)(Wbf + (long)row * 128 + kc * 8);
  }
  float bv[8];
  #pragma unroll
  for (int nt = 0; nt < 8; ++nt) bv[nt] = bias[nt * 16 + l15];

  // prologue: load first tile into named registers
  float4 p0 = z4, p1 = z4, p2 = z4, p3 = z4, p4 = z4, p5 = z4, p6 = z4, p7 = z4;
  {
    long row0 = (long)blockIdx.x * 64;
    bool v0 = row0 + r0 < rows, v1 = row0 + r0 + 16 < rows;
    bool v2 = row0 + r0 + 32 < rows, v3 = row0 + r0 + 48 < rows;
    const float4* s0 = (const float4*)(x + (row0 + r0) * 128 + kc0 * 8);
    const float4* s1 = (const float4*)(x + (row0 + r0 + 16) * 128 + kc0 * 8);
    const float4* s2 = (const float4*)(x + (row0 + r0 + 32) * 128 + kc0 * 8);
    const float4* s3 = (const float4*)(x + (row0 + r0 + 48) * 128 + kc0 * 8);
    if (v0) { p0 = s0[0]; p1 = s0[1]; }
    if (v1) { p2 = s1[0]; p3 = s1[1]; }
    if (v2) { p4 = s2[0]; p5 = s2[1]; }
    if (v3) { p6 = s3[0]; p7 = s3[1]; }
  }

  for (int tile = blockIdx.x; tile < ntiles; tile += gridDim.x) {
    const long row0 = (long)tile * 64;
    // ---- commit current tile to LDS (swizzled) ----
    *(bf16x8*)(&sA[swz_idx(r0, kc0)]) = cvt8(p0, p1);
    *(bf16x8*)(&sA[swz_idx(r0 + 16, kc0)]) = cvt8(p2, p3);
    *(bf16x8*)(&sA[swz_idx(r0 + 32, kc0)]) = cvt8(p4, p5);
    *(bf16x8*)(&sA[swz_idx(r0 + 48, kc0)]) = cvt8(p6, p7);
    __syncthreads();

    // ---- issue next tile's loads (overlap with MFMA + epilogue) ----
    float4 n0 = z4, n1 = z4, n2 = z4, n3 = z4, n4 = z4, n5 = z4, n6 = z4, n7 = z4;
    {
      int next = tile + gridDim.x;
      if (next < ntiles) {
        long rn = (long)next * 64;
        bool v0 = rn + r0 < rows, v1 = rn + r0 + 16 < rows;
        bool v2 = rn + r0 + 32 < rows, v3 = rn + r0 + 48 < rows;
        const float4* s0 = (const float4*)(x + (rn + r0) * 128 + kc0 * 8);
        const float4* s1 = (const float4*)(x + (rn + r0 + 16) * 128 + kc0 * 8);
        const float4* s2 = (const float4*)(x + (rn + r0 + 32) * 128 + kc0 * 8);
        const float4* s3 = (const float4*)(x + (rn + r0 + 48) * 128 + kc0 * 8);
        if (v0) { n0 = s0[0]; n1 = s0[1]; }
        if (v1) { n2 = s1[0]; n3 = s1[1]; }
        if (v2) { n4 = s2[0]; n5 = s2[1]; }
        if (v3) { n6 = s3[0]; n7 = s3[1]; }
      }
    }

    // ---- MFMA: wave's own 16-row band x 128 cols ----
    f32x4 acc[8];
    #pragma unroll
    for (int nt = 0; nt < 8; ++nt) acc[nt] = f32x4{0.f, 0.f, 0.f, 0.f};
    const int mrow = wv * 16 + l15;
    #pragma unroll
    for (int ks = 0; ks < 4; ++ks) {
      bf16x8 af = *(const bf16x8*)(&sA[swz_idx(mrow, ks * 4 + kg)]);
      #pragma unroll
      for (int nt = 0; nt < 8; ++nt) {
        bf16x8 bfr = *(const bf16x8*)(&sB[swz_idx(nt * 16 + l15, ks * 4 + kg)]);
        acc[nt] = __builtin_amdgcn_mfma_f32_16x16x32_bf16(af, bfr, acc[nt], 0, 0, 0);
      }
    }

    // ---- epilogue: overwrite own band of sA with linear bf16 results ----
    #pragma unroll
    for (int nt = 0; nt < 8; ++nt) {
      int col = nt * 16 + l15;
      #pragma unroll
      for (int j = 0; j < 4; ++j) {
        int brow = wv * 16 + kg * 4 + j;
        __bf16 hb = (__bf16)(acc[nt][j] + bv[nt]);
        sA[brow * 128 + col] = __builtin_bit_cast(ushort, hb);
      }
    }
    // ---- coalesced xl stores from own band (wave-local) ----
    #pragma unroll
    for (int t = 0; t < 4; ++t) {
      int g = t * 64 + lane;
      int brow = g >> 4, chunk = g & 15;
      long grow = row0 + wv * 16 + brow;
      if (grow < rows) {
        bf16x8 v = *(const bf16x8*)(&sA[(wv * 16 + brow) * 128 + chunk * 8]);
        *(bf16x8*)(xl + grow * 128 + chunk * 8) = v;
      }
    }
    __syncthreads();
    p0 = n0; p1 = n1; p2 = n2; p3 = n3; p4 = n4; p5 = n5; p6 = n6; p7 = n7;
  }
}

// ---- small GEMM: out[r, c] = bias[c] + sum_k A[r,k] * W[c,k], W pre-converted bf16 ----
__global__ __launch_bounds__(256) void k_gemm128(const float* __restrict__ A,
                                                 const __bf16* __restrict__ W,
                                                 const float* __restrict__ bias,
                                                 float* __restrict__ out,
                                                 int rows) {
  __shared__ __align__(16) ushort sB[128 * 128];
  __shared__ __align__(16) ushort sA[64 * 128];
  const int tid = threadIdx.x;
  const long row0 = (long)blockIdx.x * 64;
  for (int c = tid; c < 128 * 16; c += 256) {
    int row = c >> 4, kc = c & 15;
    *(bf16x8*)(&sB[swz_idx(row, kc)]) = *(const bf16x8*)(W + (long)row * 128 + kc * 8);
  }
  for (int c = tid; c < 64 * 16; c += 256) {
    int r = c >> 4, kc = c & 15;
    long gr = row0 + r;
    bf16x8 v;
    if (gr < rows) {
      const float4* src = (const float4*)(A + gr * 128 + kc * 8);
      v = cvt8(src[0], src[1]);
    } else {
      #pragma unroll
      for (int q = 0; q < 8; ++q) v[q] = (__bf16)0.f;
    }
    *(bf16x8*)(&sA[swz_idx(r, kc)]) = v;
  }
  const int lane = tid & 63;
  const int wv = tid >> 6;
  const int l15 = lane & 15;
  const int kg = lane >> 4;
  __syncthreads();

  f32x4 acc[8];
  #pragma unroll
  for (int nt = 0; nt < 8; ++nt) acc[nt] = f32x4{0.f, 0.f, 0.f, 0.f};
  const int mrow = wv * 16 + l15;
  #pragma unroll
  for (int ks = 0; ks < 4; ++ks) {
    bf16x8 af = *(const bf16x8*)(&sA[swz_idx(mrow, ks * 4 + kg)]);
    #pragma unroll
    for (int nt = 0; nt < 8; ++nt) {
      bf16x8 bfr = *(const bf16x8*)(&sB[swz_idx(nt * 16 + l15, ks * 4 + kg)]);
      acc[nt] = __builtin_amdgcn_mfma_f32_16x16x32_bf16(af, bfr, acc[nt], 0, 0, 0);
    }
  }
  #pragma unroll
  for (int nt = 0; nt < 8; ++nt) {
    int col = nt * 16 + l15;
    float bvv = bias[col];
    #pragma unroll
    for (int j = 0; j < 4; ++j) {
      long r = row0 + wv * 16 + kg * 4 + j;
      if (r < rows) out[r * 128 + col] = acc[nt][j] + bvv;
    }
  }
}

// ---- fused GATv2: 4 rows per iteration, 16-lane groups, online softmax ----
__global__ __launch_bounds__(256) void k_gat(const __bf16* __restrict__ xl,
                                             const float* __restrict__ xr,
                                             const int* __restrict__ seg,
                                             const float* __restrict__ att,
                                             const float* __restrict__ gat_bias,
                                             float* __restrict__ h, int G) {
  int wid = (blockIdx.x << 2) + (threadIdx.x >> 6);
  if (wid >= G) return;
  int lane = threadIdx.x & 63;
  int grp = lane >> 4, li = lane & 15;
  int s = seg[wid], e = seg[wid + 1];
  int d0 = li * 8;

  const float* xrp = xr + (long)wid * G_DIM + d0;
  float xrv[8], atv[8];
  {
    float4 a0 = *(const float4*)(xrp);
    float4 a1 = *(const float4*)(xrp + 4);
    float4 t0 = *(const float4*)(att + d0);
    float4 t1 = *(const float4*)(att + d0 + 4);
    xrv[0]=a0.x; xrv[1]=a0.y; xrv[2]=a0.z; xrv[3]=a0.w;
    xrv[4]=a1.x; xrv[5]=a1.y; xrv[6]=a1.z; xrv[7]=a1.w;
    atv[0]=t0.x; atv[1]=t0.y; atv[2]=t0.z; atv[3]=t0.w;
    atv[4]=t1.x; atv[5]=t1.y; atv[6]=t1.z; atv[7]=t1.w;
  }

  float m = -1e30f, den = 0.f;
  float acc[8];
  #pragma unroll
  for (int q = 0; q < 8; ++q) acc[q] = 0.f;

  for (int base = s; base < e; base += 4) {
    int i = base + grp;
    bool valid = i < e;
    float xv[8];
    if (valid) {
      bf16x8 v = *(const bf16x8*)((const ushort*)xl + (long)i * G_DIM + d0);
      #pragma unroll
      for (int q = 0; q < 8; ++q) xv[q] = (float)v[q];
    } else {
      #pragma unroll
      for (int q = 0; q < 8; ++q) xv[q] = 0.f;
    }
    float p = 0.f;
    #pragma unroll
    for (int q = 0; q < 8; ++q) {
      float t = xv[q] + xrv[q];
      t = fmaxf(t, 0.f) + 0.01f * fminf(t, 0.f);
      p = fmaf(t, atv[q], p);
    }
    p += __shfl_xor(p, 1, 64);
    p += __shfl_xor(p, 2, 64);
    p += __shfl_xor(p, 4, 64);
    p += __shfl_xor(p, 8, 64);
    float pe = valid ? p : -1e30f;
    float e1 = __shfl_xor(pe, 16, 64);
    float e2 = __shfl_xor(pe, 32, 64);
    float e3 = __shfl_xor(e1, 32, 64);
    float nm = fmaxf(m, fmaxf(fmaxf(pe, e1), fmaxf(e2, e3)));
    float sc = __expf(m - nm);
    float w0 = __expf(pe - nm);
    den = den * sc + w0 + __expf(e1 - nm) + __expf(e2 - nm) + __expf(e3 - nm);
    #pragma unroll
    for (int q = 0; q < 8; ++q) acc[q] = acc[q] * sc + w0 * xv[q];
    m = nm;
  }
  #pragma unroll
  for (int q = 0; q < 8; ++q) {
    acc[q] += __shfl_xor(acc[q], 16, 64);
    acc[q] += __shfl_xor(acc[q], 32, 64);
  }
  if (grp == 0) {
    float inv = (e > s) ? 1.f / den : 0.f;
    float o[8];
    #pragma unroll
    for (int q = 0; q < 8; ++q) {
      float v = acc[q] * inv + gat_bias[d0 + q];
      o[q] = v > 0.f ? v : __expf(v) - 1.f;  // elu
    }
    float* dst = h + (long)wid * G_DIM + d0;
    *(float4*)(dst) = float4{o[0], o[1], o[2], o[3]};
    *(float4*)(dst + 4) = float4{o[4], o[5], o[6], o[7]};
  }
}

// ---- fused GRU: gi=h@W_ih.T, gh=cur@W_hh.T (bf16 W), gate math, relu -> nxt ----
__global__ __launch_bounds__(256) void k_grublock(const float* __restrict__ h,
                                                  const float* __restrict__ cur,
                                                  const __bf16* __restrict__ W_ih,
                                                  const __bf16* __restrict__ W_hh,
                                                  const float* __restrict__ b_ih,
                                                  const float* __restrict__ b_hh,
                                                  float* __restrict__ nxt, int G) {
  __shared__ __align__(16) ushort sA1[64 * 128];  // h tile
  __shared__ __align__(16) ushort sA2[64 * 128];  // cur tile
  __shared__ __align__(16) ushort sW[128 * 128];  // one gate of one W at a time
  const int tid = threadIdx.x;
  const int lane = tid & 63, wv = tid >> 6, l15 = lane & 15, kg = lane >> 4;
  const long row0 = (long)blockIdx.x * 64;
  const int mrow = wv * 16 + l15;

  for (int c = tid; c < 64 * 16; c += 256) {
    int r = c >> 4, kc = c & 15;
    long gr = row0 + r;
    const float4* s1 = (const float4*)(h + gr * 128 + kc * 8);
    const float4* s2 = (const float4*)(cur + gr * 128 + kc * 8);
    *(bf16x8*)(&sA1[swz_idx(r, kc)]) = cvt8(s1[0], s1[1]);
    *(bf16x8*)(&sA2[swz_idx(r, kc)]) = cvt8(s2[0], s2[1]);
  }

  f32x4 rp[8], zp[8], inn[8], hnn[8];
  #pragma unroll
  for (int nt = 0; nt < 8; ++nt) {
    rp[nt] = f32x4{0.f, 0.f, 0.f, 0.f};
    zp[nt] = f32x4{0.f, 0.f, 0.f, 0.f};
    inn[nt] = f32x4{0.f, 0.f, 0.f, 0.f};
    hnn[nt] = f32x4{0.f, 0.f, 0.f, 0.f};
  }

#define STAGE_W(WSRC, gate)                                                   \
  __syncthreads();                                                            \
  for (int c = tid; c < 128 * 16; c += 256) {                                 \
    int r = c >> 4, kc = c & 15;                                              \
    *(bf16x8*)(&sW[swz_idx(r, kc)]) =                                         \
        *(const bf16x8*)((WSRC) + ((long)(gate)*128 + r) * 128 + kc * 8);     \
  }                                                                           \
  __syncthreads();

#define MM(ACC, SAX)                                                          \
  _Pragma("unroll") for (int ks = 0; ks < 4; ++ks) {                          \
    bf16x8 af = *(const bf16x8*)(&SAX[swz_idx(mrow, ks * 4 + kg)]);           \
    _Pragma("unroll") for (int nt = 0; nt < 8; ++nt) {                        \
      bf16x8 bfr = *(const bf16x8*)(&sW[swz_idx(nt * 16 + l15, ks * 4 + kg)]);\
      ACC[nt] = __builtin_amdgcn_mfma_f32_16x16x32_bf16(af, bfr, ACC[nt], 0, 0, 0); \
    }                                                                         \
  }

  STAGE_W(W_ih, 0) MM(rp, sA1)
  STAGE_W(W_hh, 0) MM(rp, sA2)
  STAGE_W(W_ih, 1) MM(zp, sA1)
  STAGE_W(W_hh, 1) MM(zp, sA2)
  STAGE_W(W_ih, 2) MM(inn, sA1)
  STAGE_W(W_hh, 2) MM(hnn, sA2)
#undef STAGE_W
#undef MM

  #pragma unroll
  for (int nt = 0; nt < 8; ++nt) {
    int col = nt * 16 + l15;
    float bir = b_ih[col], biz = b_ih[col + 128], bin = b_ih[col + 256];
    float bhr = b_hh[col], bhz = b_hh[col + 128], bhn = b_hh[col + 256];
    #pragma unroll
    for (int j = 0; j < 4; ++j) {
      long r = row0 + wv * 16 + kg * 4 + j;
      if (r >= G) continue;
      float pre_r = rp[nt][j] + bir + bhr;
      float pre_z = zp[nt][j] + biz + bhz;
      float rr = 1.f / (1.f + __expf(-pre_r));
      float zz = 1.f / (1.f + __expf(-pre_z));
      float nn = tanhf(inn[nt][j] + bin + rr * (hnn[nt][j] + bhn));
      float hp = cur[r * 128 + col];
      nxt[r * 128 + col] = fmaxf((1.f - zz) * nn + zz * hp, 0.f);
    }
  }
}

extern "C" void kernel_launch(void* const* d_in, const int* in_sizes, int n_in,
                              void* d_out, int out_size, void* d_ws, size_t ws_size,
                              hipStream_t stream) {
  const float* x        = (const float*)d_in[0];
  const int*   batch    = (const int*)d_in[1];
  const float* Wl       = (const float*)d_in[2];
  const float* bl       = (const float*)d_in[3];
  const float* Wr       = (const float*)d_in[4];
  const float* br       = (const float*)d_in[5];
  const float* att      = (const float*)d_in[6];
  const float* gat_bias = (const float*)d_in[7];
  const float* W_ih     = (const float*)d_in[8];
  const float* W_hh     = (const float*)d_in[9];
  const float* b_ih     = (const float*)d_in[10];
  const float* b_hh     = (const float*)d_in[11];
  const float* Wfc      = (const float*)d_in[12];
  const float* bfc      = (const float*)d_in[13];
  const int N = in_sizes[1];
  const int G = out_size / G_DIM;
  float* outf = (float*)d_out;

  char* ws = (char*)d_ws;
  size_t off = 0;
  auto alloc = [&](size_t bytes) -> void* {
    void* p = ws + off;
    off = (off + bytes + 255) & ~(size_t)255;
    return p;
  };
  int*    seg   = (int*)alloc(((size_t)G + 1) * sizeof(int));
  float*  out_a = (float*)alloc((size_t)G * G_DIM * sizeof(float));
  float*  out_b = (float*)alloc((size_t)G * G_DIM * sizeof(float));
  float*  xr    = (float*)alloc((size_t)G * G_DIM * sizeof(float));
  float*  hbuf  = (float*)alloc((size_t)G * G_DIM * sizeof(float));
  __bf16* wsW   = (__bf16*)alloc((size_t)147456 * sizeof(ushort));
  __bf16* xl    = (__bf16*)alloc((size_t)N * G_DIM * sizeof(ushort));
  (void)ws_size; (void)n_in;

  __bf16* Wlb  = wsW;
  __bf16* Wrb  = wsW + 16384;
  __bf16* Wihb = wsW + 32768;
  __bf16* Whhb = wsW + 81920;
  __bf16* Wfcb = wsW + 131072;

  k_wcvt<<<(147456 / 8 + 255) / 256, 256, 0, stream>>>(Wl, Wr, W_ih, W_hh, Wfc, wsW);
  k_seg<<<(N + 255) / 256, 256, 0, stream>>>(batch, seg, N, G);
  k_pool<<<(G + 3) / 4, 256, 0, stream>>>(x, seg, out_a, G);

  const int ntiles_big = (N + 63) / 64;
  k_xlgemm<<<768, 256, 0, stream>>>(Wlb, x, bl, xl, N, ntiles_big);

  const int ntiles_g = (G + 63) / 64;
  const float* cur = out_a;
  float* nxt = out_b;
  for (int t = 0; t < 3; ++t) {
    k_gemm128<<<ntiles_g, 256, 0, stream>>>(cur, Wrb, br, xr, G);
    k_gat<<<(G + 3) / 4, 256, 0, stream>>>(xl, xr, seg, att, gat_bias, hbuf, G);
    k_grublock<<<ntiles_g, 256, 0, stream>>>(hbuf, cur, Wihb, Whhb, b_ih, b_hh, nxt, G);
    const float* tmp = cur;
    cur = nxt;
    nxt = (float*)tmp;
  }
  k_gemm128<<<ntiles_g, 256, 0, stream>>>(cur, Wfcb, bfc, outf, G);
}

// Round 6
// 295.158 us; speedup vs baseline: 3.0087x; 1.1850x over previous
//
#include <hip/hip_runtime.h>
#include <hip/hip_bf16.h>

typedef __bf16 bf16x8 __attribute__((ext_vector_type(8)));
typedef float f32x4 __attribute__((ext_vector_type(4)));

#define G_DIM 128

// ---- helpers ----
__device__ __forceinline__ float bf2f(ushort u) {
  return __uint_as_float(((unsigned int)u) << 16);
}

__device__ __forceinline__ bf16x8 cvt8(float4 f0, float4 f1) {
  bf16x8 v;
  v[0] = (__bf16)f0.x; v[1] = (__bf16)f0.y; v[2] = (__bf16)f0.z; v[3] = (__bf16)f0.w;
  v[4] = (__bf16)f1.x; v[5] = (__bf16)f1.y; v[6] = (__bf16)f1.z; v[7] = (__bf16)f1.w;
  return v;
}

// swizzled ushort index into a row-major [rows][128] bf16 LDS tile.
__device__ __forceinline__ int swz_idx(int row, int kc) {
  return (row * 128 + kc * 8) ^ ((row & 7) << 3);
}

// ---- W fp32 -> bf16 pre-conversion (5 matrices packed into one dst) ----
// layout (elem offsets): Wl@0, Wr@16384, W_ih@32768, W_hh@81920, Wfc@131072, total 147456
__global__ void k_wcvt(const float* __restrict__ Wl, const float* __restrict__ Wr,
                       const float* __restrict__ Wih, const float* __restrict__ Whh,
                       const float* __restrict__ Wfc, __bf16* __restrict__ dst) {
  int i = blockIdx.x * blockDim.x + threadIdx.x;
  if (i >= 147456 / 8) return;
  int e = i * 8;
  const float* src; int off;
  if (e < 16384)       { src = Wl;  off = e; }
  else if (e < 32768)  { src = Wr;  off = e - 16384; }
  else if (e < 81920)  { src = Wih; off = e - 32768; }
  else if (e < 131072) { src = Whh; off = e - 81920; }
  else                 { src = Wfc; off = e - 131072; }
  float4 a = ((const float4*)(src + off))[0];
  float4 b = ((const float4*)(src + off))[1];
  *(bf16x8*)(dst + e) = cvt8(a, b);
}

// ---- segment ranges from sorted batch ----
__global__ void k_seg(const int* __restrict__ batch, int* __restrict__ seg, int n, int g) {
  int i = blockIdx.x * blockDim.x + threadIdx.x;
  if (i >= n) return;
  int b = batch[i];
  int prev = (i == 0) ? -1 : batch[i - 1];
  for (int q = prev + 1; q <= b; ++q) seg[q] = i;
  if (i == n - 1) {
    for (int q = b + 1; q <= g; ++q) seg[q] = n;
  }
}

// ---- fused GEMM + band pool: xl = bf16(x @ Wl.T + bl); per-band segment sums.
// Band = 16-row slice (one wave). Interior segments -> exclusive pool[g] store.
// Band-edge segments -> edgebuf[band][slot] (slot0 if segment starts band, else 1).
// NO atomics anywhere.
__global__ __launch_bounds__(256, 3) void k_xlgemm(const __bf16* __restrict__ Wbf,
                                                   const float* __restrict__ x,
                                                   const float* __restrict__ bias,
                                                   const int* __restrict__ batch,
                                                   __bf16* __restrict__ xl,
                                                   float* __restrict__ pool,
                                                   float* __restrict__ edgebuf,
                                                   int rows, int ntiles) {
  __shared__ __align__(16) ushort sB[128 * 128];  // W, swizzled, persistent
  __shared__ __align__(16) ushort sA[64 * 128];   // x tile (swz) -> reused as xl tile (linear)
  __shared__ int sBatchE[66];                     // batch[row0-1 .. row0+64]
  const int tid = threadIdx.x;
  const int lane = tid & 63;
  const int wv = tid >> 6;
  const int l15 = lane & 15;
  const int kg = lane >> 4;
  const int r0 = tid >> 4, kc0 = tid & 15;
  const float4 z4 = float4{0.f, 0.f, 0.f, 0.f};

  // stage W (bf16, already converted) once per block
  for (int c = tid; c < 128 * 16; c += 256) {
    int row = c >> 4, kc = c & 15;
    *(bf16x8*)(&sB[swz_idx(row, kc)]) = *(const bf16x8*)(Wbf + (long)row * 128 + kc * 8);
  }
  float bv[8];
  #pragma unroll
  for (int nt = 0; nt < 8; ++nt) bv[nt] = bias[nt * 16 + l15];

  // prologue: load first tile into named registers
  float4 p0 = z4, p1 = z4, p2 = z4, p3 = z4, p4 = z4, p5 = z4, p6 = z4, p7 = z4;
  {
    long row0 = (long)blockIdx.x * 64;
    bool v0 = row0 + r0 < rows, v1 = row0 + r0 + 16 < rows;
    bool v2 = row0 + r0 + 32 < rows, v3 = row0 + r0 + 48 < rows;
    const float4* s0 = (const float4*)(x + (row0 + r0) * 128 + kc0 * 8);
    const float4* s1 = (const float4*)(x + (row0 + r0 + 16) * 128 + kc0 * 8);
    const float4* s2 = (const float4*)(x + (row0 + r0 + 32) * 128 + kc0 * 8);
    const float4* s3 = (const float4*)(x + (row0 + r0 + 48) * 128 + kc0 * 8);
    if (v0) { p0 = s0[0]; p1 = s0[1]; }
    if (v1) { p2 = s1[0]; p3 = s1[1]; }
    if (v2) { p4 = s2[0]; p5 = s2[1]; }
    if (v3) { p6 = s3[0]; p7 = s3[1]; }
  }

  for (int tile = blockIdx.x; tile < ntiles; tile += gridDim.x) {
    const long row0 = (long)tile * 64;
    // ---- commit current tile to LDS (swizzled) + batch ext ----
    *(bf16x8*)(&sA[swz_idx(r0, kc0)]) = cvt8(p0, p1);
    *(bf16x8*)(&sA[swz_idx(r0 + 16, kc0)]) = cvt8(p2, p3);
    *(bf16x8*)(&sA[swz_idx(r0 + 32, kc0)]) = cvt8(p4, p5);
    *(bf16x8*)(&sA[swz_idx(r0 + 48, kc0)]) = cvt8(p6, p7);
    if (tid < 66) {
      long idx = row0 - 1 + tid;
      sBatchE[tid] = (idx < 0) ? -3 : (idx < rows ? batch[idx] : -2);
    }
    __syncthreads();

    // ---- issue next tile's loads (overlap with MFMA + pool + epilogue) ----
    float4 n0 = z4, n1 = z4, n2 = z4, n3 = z4, n4 = z4, n5 = z4, n6 = z4, n7 = z4;
    {
      int next = tile + gridDim.x;
      if (next < ntiles) {
        long rn = (long)next * 64;
        bool v0 = rn + r0 < rows, v1 = rn + r0 + 16 < rows;
        bool v2 = rn + r0 + 32 < rows, v3 = rn + r0 + 48 < rows;
        const float4* s0 = (const float4*)(x + (rn + r0) * 128 + kc0 * 8);
        const float4* s1 = (const float4*)(x + (rn + r0 + 16) * 128 + kc0 * 8);
        const float4* s2 = (const float4*)(x + (rn + r0 + 32) * 128 + kc0 * 8);
        const float4* s3 = (const float4*)(x + (rn + r0 + 48) * 128 + kc0 * 8);
        if (v0) { n0 = s0[0]; n1 = s0[1]; }
        if (v1) { n2 = s1[0]; n3 = s1[1]; }
        if (v2) { n4 = s2[0]; n5 = s2[1]; }
        if (v3) { n6 = s3[0]; n7 = s3[1]; }
      }
    }

    // ---- MFMA: wave's own 16-row band x 128 cols ----
    f32x4 acc[8];
    #pragma unroll
    for (int nt = 0; nt < 8; ++nt) acc[nt] = f32x4{0.f, 0.f, 0.f, 0.f};
    const int mrow = wv * 16 + l15;
    #pragma unroll
    for (int ks = 0; ks < 4; ++ks) {
      bf16x8 af = *(const bf16x8*)(&sA[swz_idx(mrow, ks * 4 + kg)]);
      #pragma unroll
      for (int nt = 0; nt < 8; ++nt) {
        bf16x8 bfr = *(const bf16x8*)(&sB[swz_idx(nt * 16 + l15, ks * 4 + kg)]);
        acc[nt] = __builtin_amdgcn_mfma_f32_16x16x32_bf16(af, bfr, acc[nt], 0, 0, 0);
      }
    }

    // ---- band pool: wave's 16-row band; wave-uniform segment walk; no atomics ----
    {
      const int rbeg = wv * 16;
      const long band = (long)tile * 4 + wv;
      int r = 0;
      while (r < 16) {
        int g = sBatchE[1 + rbeg + r];
        if (g < 0) break;
        int e = r + 1;
        while (e < 16 && sBatchE[1 + rbeg + e] == g) ++e;
        float s8[8];
        #pragma unroll
        for (int q = 0; q < 8; ++q) s8[q] = 0.f;
        #pragma unroll
        for (int j = 0; j < 4; ++j) {
          int row = kg + 4 * j;
          if (row >= r && row < e) {
            bf16x8 v = *(const bf16x8*)(&sA[swz_idx(rbeg + row, l15)]);
            #pragma unroll
            for (int q = 0; q < 8; ++q) s8[q] += (float)v[q];
          }
        }
        #pragma unroll
        for (int q = 0; q < 8; ++q) {
          s8[q] += __shfl_xor(s8[q], 16, 64);
          s8[q] += __shfl_xor(s8[q], 32, 64);
        }
        bool lext = (r == 0) && (sBatchE[rbeg] == g);
        bool rext = (e == 16) && (sBatchE[1 + rbeg + 16] == g);
        if (kg == 0) {
          float* dst = (!lext && !rext)
              ? (pool + (long)g * 128)
              : (edgebuf + (band * 2 + ((r == 0) ? 0 : 1)) * 128);
          *(float4*)(dst + l15 * 8) = float4{s8[0], s8[1], s8[2], s8[3]};
          *(float4*)(dst + l15 * 8 + 4) = float4{s8[4], s8[5], s8[6], s8[7]};
        }
        r = e;
      }
    }

    // ---- epilogue: overwrite own band of sA with linear bf16 results ----
    #pragma unroll
    for (int nt = 0; nt < 8; ++nt) {
      int col = nt * 16 + l15;
      #pragma unroll
      for (int j = 0; j < 4; ++j) {
        int brow = wv * 16 + kg * 4 + j;
        __bf16 hb = (__bf16)(acc[nt][j] + bv[nt]);
        sA[brow * 128 + col] = __builtin_bit_cast(ushort, hb);
      }
    }
    // ---- coalesced xl stores from own band (wave-local) ----
    #pragma unroll
    for (int t = 0; t < 4; ++t) {
      int g = t * 64 + lane;
      int brow = g >> 4, chunk = g & 15;
      long grow = row0 + wv * 16 + brow;
      if (grow < rows) {
        bf16x8 v = *(const bf16x8*)(&sA[(wv * 16 + brow) * 128 + chunk * 8]);
        *(bf16x8*)(xl + grow * 128 + chunk * 8) = v;
      }
    }
    __syncthreads();
    p0 = n0; p1 = n1; p2 = n2; p3 = n3; p4 = n4; p5 = n5; p6 = n6; p7 = n7;
  }
}

// ---- pool combine: pool[g] = relu(direct or sum of edge slots). Wave per graph. ----
__global__ __launch_bounds__(256) void k_poolfix(const int* __restrict__ seg,
                                                 const float* __restrict__ edgebuf,
                                                 float* __restrict__ pool, int G) {
  int wid = (blockIdx.x << 2) + (threadIdx.x >> 6);
  if (wid >= G) return;
  int lane = threadIdx.x & 63;
  int s = seg[wid], e = seg[wid + 1];
  float vx = 0.f, vy = 0.f;
  float* prow = pool + (long)wid * 128;
  if (s < e) {
    int b0 = s >> 4, b1 = (e - 1) >> 4;
    if (b0 == b1) {
      float2 u = *(const float2*)(prow + lane * 2);
      vx = u.x; vy = u.y;
    } else {
      for (int t = b0; t <= b1; ++t) {
        int slot = (t == b0 && (s > (t << 4))) ? 1 : 0;
        const float* src = edgebuf + ((long)t * 2 + slot) * 128;
        float2 u = *(const float2*)(src + lane * 2);
        vx += u.x; vy += u.y;
      }
    }
  }
  *(float2*)(prow + lane * 2) = float2{fmaxf(vx, 0.f), fmaxf(vy, 0.f)};
}

// ---- small GEMM: out[r, c] = bias[c] + sum_k A[r,k] * W[c,k], W pre-converted bf16 ----
__global__ __launch_bounds__(256) void k_gemm128(const float* __restrict__ A,
                                                 const __bf16* __restrict__ W,
                                                 const float* __restrict__ bias,
                                                 float* __restrict__ out,
                                                 int rows) {
  __shared__ __align__(16) ushort sB[128 * 128];
  __shared__ __align__(16) ushort sA[64 * 128];
  const int tid = threadIdx.x;
  const long row0 = (long)blockIdx.x * 64;
  for (int c = tid; c < 128 * 16; c += 256) {
    int row = c >> 4, kc = c & 15;
    *(bf16x8*)(&sB[swz_idx(row, kc)]) = *(const bf16x8*)(W + (long)row * 128 + kc * 8);
  }
  for (int c = tid; c < 64 * 16; c += 256) {
    int r = c >> 4, kc = c & 15;
    long gr = row0 + r;
    bf16x8 v;
    if (gr < rows) {
      const float4* src = (const float4*)(A + gr * 128 + kc * 8);
      v = cvt8(src[0], src[1]);
    } else {
      #pragma unroll
      for (int q = 0; q < 8; ++q) v[q] = (__bf16)0.f;
    }
    *(bf16x8*)(&sA[swz_idx(r, kc)]) = v;
  }
  const int lane = tid & 63;
  const int wv = tid >> 6;
  const int l15 = lane & 15;
  const int kg = lane >> 4;
  __syncthreads();

  f32x4 acc[8];
  #pragma unroll
  for (int nt = 0; nt < 8; ++nt) acc[nt] = f32x4{0.f, 0.f, 0.f, 0.f};
  const int mrow = wv * 16 + l15;
  #pragma unroll
  for (int ks = 0; ks < 4; ++ks) {
    bf16x8 af = *(const bf16x8*)(&sA[swz_idx(mrow, ks * 4 + kg)]);
    #pragma unroll
    for (int nt = 0; nt < 8; ++nt) {
      bf16x8 bfr = *(const bf16x8*)(&sB[swz_idx(nt * 16 + l15, ks * 4 + kg)]);
      acc[nt] = __builtin_amdgcn_mfma_f32_16x16x32_bf16(af, bfr, acc[nt], 0, 0, 0);
    }
  }
  #pragma unroll
  for (int nt = 0; nt < 8; ++nt) {
    int col = nt * 16 + l15;
    float bvv = bias[col];
    #pragma unroll
    for (int j = 0; j < 4; ++j) {
      long r = row0 + wv * 16 + kg * 4 + j;
      if (r < rows) out[r * 128 + col] = acc[nt][j] + bvv;
    }
  }
}

// ---- fused GATv2: 4 rows per iteration, 16-lane groups, online softmax ----
__global__ __launch_bounds__(256) void k_gat(const __bf16* __restrict__ xl,
                                             const float* __restrict__ xr,
                                             const int* __restrict__ seg,
                                             const float* __restrict__ att,
                                             const float* __restrict__ gat_bias,
                                             float* __restrict__ h, int G) {
  int wid = (blockIdx.x << 2) + (threadIdx.x >> 6);
  if (wid >= G) return;
  int lane = threadIdx.x & 63;
  int grp = lane >> 4, li = lane & 15;
  int s = seg[wid], e = seg[wid + 1];
  int d0 = li * 8;

  const float* xrp = xr + (long)wid * G_DIM + d0;
  float xrv[8], atv[8];
  {
    float4 a0 = *(const float4*)(xrp);
    float4 a1 = *(const float4*)(xrp + 4);
    float4 t0 = *(const float4*)(att + d0);
    float4 t1 = *(const float4*)(att + d0 + 4);
    xrv[0]=a0.x; xrv[1]=a0.y; xrv[2]=a0.z; xrv[3]=a0.w;
    xrv[4]=a1.x; xrv[5]=a1.y; xrv[6]=a1.z; xrv[7]=a1.w;
    atv[0]=t0.x; atv[1]=t0.y; atv[2]=t0.z; atv[3]=t0.w;
    atv[4]=t1.x; atv[5]=t1.y; atv[6]=t1.z; atv[7]=t1.w;
  }

  float m = -1e30f, den = 0.f;
  float acc[8];
  #pragma unroll
  for (int q = 0; q < 8; ++q) acc[q] = 0.f;

  for (int base = s; base < e; base += 4) {
    int i = base + grp;
    bool valid = i < e;
    float xv[8];
    if (valid) {
      bf16x8 v = *(const bf16x8*)((const ushort*)xl + (long)i * G_DIM + d0);
      #pragma unroll
      for (int q = 0; q < 8; ++q) xv[q] = (float)v[q];
    } else {
      #pragma unroll
      for (int q = 0; q < 8; ++q) xv[q] = 0.f;
    }
    float p = 0.f;
    #pragma unroll
    for (int q = 0; q < 8; ++q) {
      float t = xv[q] + xrv[q];
      t = fmaxf(t, 0.f) + 0.01f * fminf(t, 0.f);
      p = fmaf(t, atv[q], p);
    }
    p += __shfl_xor(p, 1, 64);
    p += __shfl_xor(p, 2, 64);
    p += __shfl_xor(p, 4, 64);
    p += __shfl_xor(p, 8, 64);
    float pe = valid ? p : -1e30f;
    float e1 = __shfl_xor(pe, 16, 64);
    float e2 = __shfl_xor(pe, 32, 64);
    float e3 = __shfl_xor(e1, 32, 64);
    float nm = fmaxf(m, fmaxf(fmaxf(pe, e1), fmaxf(e2, e3)));
    float sc = __expf(m - nm);
    float w0 = __expf(pe - nm);
    den = den * sc + w0 + __expf(e1 - nm) + __expf(e2 - nm) + __expf(e3 - nm);
    #pragma unroll
    for (int q = 0; q < 8; ++q) acc[q] = acc[q] * sc + w0 * xv[q];
    m = nm;
  }
  #pragma unroll
  for (int q = 0; q < 8; ++q) {
    acc[q] += __shfl_xor(acc[q], 16, 64);
    acc[q] += __shfl_xor(acc[q], 32, 64);
  }
  if (grp == 0) {
    float inv = (e > s) ? 1.f / den : 0.f;
    float o[8];
    #pragma unroll
    for (int q = 0; q < 8; ++q) {
      float v = acc[q] * inv + gat_bias[d0 + q];
      o[q] = v > 0.f ? v : __expf(v) - 1.f;  // elu
    }
    float* dst = h + (long)wid * G_DIM + d0;
    *(float4*)(dst) = float4{o[0], o[1], o[2], o[3]};
    *(float4*)(dst + 4) = float4{o[4], o[5], o[6], o[7]};
  }
}

// ---- fused GRU with ping-pong W staging: 6 MFMA steps, 6 barriers, loads overlap MM ----
__global__ __launch_bounds__(256) void k_grublock(const float* __restrict__ h,
                                                  const float* __restrict__ cur,
                                                  const __bf16* __restrict__ W_ih,
                                                  const __bf16* __restrict__ W_hh,
                                                  const float* __restrict__ b_ih,
                                                  const float* __restrict__ b_hh,
                                                  float* __restrict__ nxt, int G) {
  __shared__ __align__(16) ushort sA1[64 * 128];     // h tile
  __shared__ __align__(16) ushort sA2[64 * 128];     // cur tile
  __shared__ __align__(16) ushort sW[2][128 * 128];  // ping-pong gate buffers (64 KB)
  const int tid = threadIdx.x;
  const int lane = tid & 63, wv = tid >> 6, l15 = lane & 15, kg = lane >> 4;
  const long row0 = (long)blockIdx.x * 64;
  const int mrow = wv * 16 + l15;
  const int r0w = tid >> 4, kcw = tid & 15;

  // stage A tiles + first W gate (W_ih g0) into sW[0]
  for (int c = tid; c < 64 * 16; c += 256) {
    int r = c >> 4, kc = c & 15;
    long gr = row0 + r;
    const float4* s1 = (const float4*)(h + gr * 128 + kc * 8);
    const float4* s2 = (const float4*)(cur + gr * 128 + kc * 8);
    *(bf16x8*)(&sA1[swz_idx(r, kc)]) = cvt8(s1[0], s1[1]);
    *(bf16x8*)(&sA2[swz_idx(r, kc)]) = cvt8(s2[0], s2[1]);
  }
  {
    const __bf16* wp = W_ih + (long)r0w * 128 + kcw * 8;
    #pragma unroll
    for (int k = 0; k < 8; ++k)
      *(bf16x8*)(&sW[0][swz_idx(r0w + 16 * k, kcw)]) = *(const bf16x8*)(wp + k * 2048);
  }
  __syncthreads();

  f32x4 rp[8], zp[8], inn[8], hnn[8];
  #pragma unroll
  for (int nt = 0; nt < 8; ++nt) {
    rp[nt] = f32x4{0.f, 0.f, 0.f, 0.f};
    zp[nt] = f32x4{0.f, 0.f, 0.f, 0.f};
    inn[nt] = f32x4{0.f, 0.f, 0.f, 0.f};
    hnn[nt] = f32x4{0.f, 0.f, 0.f, 0.f};
  }

#define MM(ACC, SAX, WB)                                                      \
  _Pragma("unroll") for (int ks = 0; ks < 4; ++ks) {                          \
    bf16x8 af = *(const bf16x8*)(&SAX[swz_idx(mrow, ks * 4 + kg)]);           \
    _Pragma("unroll") for (int nt = 0; nt < 8; ++nt) {                        \
      bf16x8 bfr = *(const bf16x8*)(&(WB)[swz_idx(nt * 16 + l15, ks * 4 + kg)]); \
      ACC[nt] = __builtin_amdgcn_mfma_f32_16x16x32_bf16(af, bfr, ACC[nt], 0, 0, 0); \
    }                                                                         \
  }

#define STEP(S, NEXTSRC, ACC, SAX, ISLAST)                                    \
  {                                                                           \
    bf16x8 w0, w1, w2, w3, w4, w5, w6, w7;                                    \
    if (!(ISLAST)) {                                                          \
      const __bf16* wp = (NEXTSRC) + (long)r0w * 128 + kcw * 8;               \
      w0 = *(const bf16x8*)(wp + 0 * 2048); w1 = *(const bf16x8*)(wp + 1 * 2048); \
      w2 = *(const bf16x8*)(wp + 2 * 2048); w3 = *(const bf16x8*)(wp + 3 * 2048); \
      w4 = *(const bf16x8*)(wp + 4 * 2048); w5 = *(const bf16x8*)(wp + 5 * 2048); \
      w6 = *(const bf16x8*)(wp + 6 * 2048); w7 = *(const bf16x8*)(wp + 7 * 2048); \
    }                                                                         \
    MM(ACC, SAX, sW[(S) & 1])                                                 \
    if (!(ISLAST)) {                                                          \
      ushort* wb = sW[((S) + 1) & 1];                                         \
      *(bf16x8*)(&wb[swz_idx(r0w + 0, kcw)])   = w0;                          \
      *(bf16x8*)(&wb[swz_idx(r0w + 16, kcw)])  = w1;                          \
      *(bf16x8*)(&wb[swz_idx(r0w + 32, kcw)])  = w2;                          \
      *(bf16x8*)(&wb[swz_idx(r0w + 48, kcw)])  = w3;                          \
      *(bf16x8*)(&wb[swz_idx(r0w + 64, kcw)])  = w4;                          \
      *(bf16x8*)(&wb[swz_idx(r0w + 80, kcw)])  = w5;                          \
      *(bf16x8*)(&wb[swz_idx(r0w + 96, kcw)])  = w6;                          \
      *(bf16x8*)(&wb[swz_idx(r0w + 112, kcw)]) = w7;                          \
    }                                                                         \
    __syncthreads();                                                          \
  }

  STEP(0, W_hh,          rp,  sA1, false)
  STEP(1, W_ih + 16384,  rp,  sA2, false)
  STEP(2, W_hh + 16384,  zp,  sA1, false)
  STEP(3, W_ih + 32768,  zp,  sA2, false)
  STEP(4, W_hh + 32768,  inn, sA1, false)
  STEP(5, W_hh,          hnn, sA2, true)
#undef STEP
#undef MM

  #pragma unroll
  for (int nt = 0; nt < 8; ++nt) {
    int col = nt * 16 + l15;
    float bir = b_ih[col], biz = b_ih[col + 128], bin = b_ih[col + 256];
    float bhr = b_hh[col], bhz = b_hh[col + 128], bhn = b_hh[col + 256];
    #pragma unroll
    for (int j = 0; j < 4; ++j) {
      long r = row0 + wv * 16 + kg * 4 + j;
      if (r >= G) continue;
      float pre_r = rp[nt][j] + bir + bhr;
      float pre_z = zp[nt][j] + biz + bhz;
      float rr = 1.f / (1.f + __expf(-pre_r));
      float zz = 1.f / (1.f + __expf(-pre_z));
      float nn = tanhf(inn[nt][j] + bin + rr * (hnn[nt][j] + bhn));
      float hp = cur[r * 128 + col];
      nxt[r * 128 + col] = fmaxf((1.f - zz) * nn + zz * hp, 0.f);
    }
  }
}

extern "C" void kernel_launch(void* const* d_in, const int* in_sizes, int n_in,
                              void* d_out, int out_size, void* d_ws, size_t ws_size,
                              hipStream_t stream) {
  const float* x        = (const float*)d_in[0];
  const int*   batch    = (const int*)d_in[1];
  const float* Wl       = (const float*)d_in[2];
  const float* bl       = (const float*)d_in[3];
  const float* Wr       = (const float*)d_in[4];
  const float* br       = (const float*)d_in[5];
  const float* att      = (const float*)d_in[6];
  const float* gat_bias = (const float*)d_in[7];
  const float* W_ih     = (const float*)d_in[8];
  const float* W_hh     = (const float*)d_in[9];
  const float* b_ih     = (const float*)d_in[10];
  const float* b_hh     = (const float*)d_in[11];
  const float* Wfc      = (const float*)d_in[12];
  const float* bfc      = (const float*)d_in[13];
  const int N = in_sizes[1];
  const int G = out_size / G_DIM;
  float* outf = (float*)d_out;

  const int ntiles_big = (N + 63) / 64;
  const long nbands = (long)ntiles_big * 4;

  char* ws = (char*)d_ws;
  size_t off = 0;
  auto alloc = [&](size_t bytes) -> void* {
    void* p = ws + off;
    off = (off + bytes + 255) & ~(size_t)255;
    return p;
  };
  int*    seg     = (int*)alloc(((size_t)G + 1) * sizeof(int));
  float*  out_a   = (float*)alloc((size_t)G * G_DIM * sizeof(float));
  float*  out_b   = (float*)alloc((size_t)G * G_DIM * sizeof(float));
  float*  xr      = (float*)alloc((size_t)G * G_DIM * sizeof(float));
  float*  hbuf    = (float*)alloc((size_t)G * G_DIM * sizeof(float));
  __bf16* wsW     = (__bf16*)alloc((size_t)147456 * sizeof(ushort));
  float*  edgebuf = (float*)alloc((size_t)nbands * 2 * G_DIM * sizeof(float));
  __bf16* xl      = (__bf16*)alloc((size_t)N * G_DIM * sizeof(ushort));
  (void)ws_size; (void)n_in;

  __bf16* Wlb  = wsW;
  __bf16* Wrb  = wsW + 16384;
  __bf16* Wihb = wsW + 32768;
  __bf16* Whhb = wsW + 81920;
  __bf16* Wfcb = wsW + 131072;

  k_wcvt<<<(147456 / 8 + 255) / 256, 256, 0, stream>>>(Wl, Wr, W_ih, W_hh, Wfc, wsW);
  k_seg<<<(N + 255) / 256, 256, 0, stream>>>(batch, seg, N, G);

  k_xlgemm<<<768, 256, 0, stream>>>(Wlb, x, bl, batch, xl, out_a, edgebuf, N, ntiles_big);
  k_poolfix<<<(G + 3) / 4, 256, 0, stream>>>(seg, edgebuf, out_a, G);

  const int ntiles_g = (G + 63) / 64;
  const float* cur = out_a;
  float* nxt = out_b;
  for (int t = 0; t < 3; ++t) {
    k_gemm128<<<ntiles_g, 256, 0, stream>>>(cur, Wrb, br, xr, G);
    k_gat<<<(G + 3) / 4, 256, 0, stream>>>(xl, xr, seg, att, gat_bias, hbuf, G);
    k_grublock<<<ntiles_g, 256, 0, stream>>>(hbuf, cur, Wihb, Whhb, b_ih, b_hh, nxt, G);
    const float* tmp = cur;
    cur = nxt;
    nxt = (float*)tmp;
  }
  k_gemm128<<<ntiles_g, 256, 0, stream>>>(cur, Wfcb, bfc, outf, G);
}

// Round 7
// 267.774 us; speedup vs baseline: 3.3163x; 1.1023x over previous
//
#include <hip/hip_runtime.h>
#include <hip/hip_bf16.h>

typedef __bf16 bf16x8 __attribute__((ext_vector_type(8)));
typedef float f32x4 __attribute__((ext_vector_type(4)));

#define G_DIM 128

// ---- helpers ----
__device__ __forceinline__ float bf2f(ushort u) {
  return __uint_as_float(((unsigned int)u) << 16);
}

__device__ __forceinline__ bf16x8 cvt8(float4 f0, float4 f1) {
  bf16x8 v;
  v[0] = (__bf16)f0.x; v[1] = (__bf16)f0.y; v[2] = (__bf16)f0.z; v[3] = (__bf16)f0.w;
  v[4] = (__bf16)f1.x; v[5] = (__bf16)f1.y; v[6] = (__bf16)f1.z; v[7] = (__bf16)f1.w;
  return v;
}

// swizzled ushort index into a row-major [rows][128] bf16 LDS tile.
__device__ __forceinline__ int swz_idx(int row, int kc) {
  return (row * 128 + kc * 8) ^ ((row & 7) << 3);
}

// ---- W fp32 -> bf16 pre-conversion (5 matrices packed into one dst) ----
// layout (elem offsets): Wl@0, Wr@16384, W_ih@32768, W_hh@81920, Wfc@131072, total 147456
__global__ void k_wcvt(const float* __restrict__ Wl, const float* __restrict__ Wr,
                       const float* __restrict__ Wih, const float* __restrict__ Whh,
                       const float* __restrict__ Wfc, __bf16* __restrict__ dst) {
  int i = blockIdx.x * blockDim.x + threadIdx.x;
  if (i >= 147456 / 8) return;
  int e = i * 8;
  const float* src; int off;
  if (e < 16384)       { src = Wl;  off = e; }
  else if (e < 32768)  { src = Wr;  off = e - 16384; }
  else if (e < 81920)  { src = Wih; off = e - 32768; }
  else if (e < 131072) { src = Whh; off = e - 81920; }
  else                 { src = Wfc; off = e - 131072; }
  float4 a = ((const float4*)(src + off))[0];
  float4 b = ((const float4*)(src + off))[1];
  *(bf16x8*)(dst + e) = cvt8(a, b);
}

// ---- segment ranges from sorted batch ----
__global__ void k_seg(const int* __restrict__ batch, int* __restrict__ seg, int n, int g) {
  int i = blockIdx.x * blockDim.x + threadIdx.x;
  if (i >= n) return;
  int b = batch[i];
  int prev = (i == 0) ? -1 : batch[i - 1];
  for (int q = prev + 1; q <= b; ++q) seg[q] = i;
  if (i == n - 1) {
    for (int q = b + 1; q <= g; ++q) seg[q] = n;
  }
}

// ---- fused GEMM + band pool: xl = bf16(x @ Wl.T + bl); per-band segment sums.
// Band = 16-row slice (one wave). Interior segments -> exclusive pool[g] store.
// Band-edge segments -> edgebuf[band][slot]. NO atomics anywhere.
__global__ __launch_bounds__(256, 3) void k_xlgemm(const __bf16* __restrict__ Wbf,
                                                   const float* __restrict__ x,
                                                   const float* __restrict__ bias,
                                                   const int* __restrict__ batch,
                                                   __bf16* __restrict__ xl,
                                                   float* __restrict__ pool,
                                                   float* __restrict__ edgebuf,
                                                   int rows, int ntiles) {
  __shared__ __align__(16) ushort sB[128 * 128];  // W, swizzled, persistent
  __shared__ __align__(16) ushort sA[64 * 128];   // x tile (swz) -> reused as xl tile (linear)
  __shared__ int sBatchE[66];                     // batch[row0-1 .. row0+64]
  const int tid = threadIdx.x;
  const int lane = tid & 63;
  const int wv = tid >> 6;
  const int l15 = lane & 15;
  const int kg = lane >> 4;
  const int r0 = tid >> 4, kc0 = tid & 15;
  const float4 z4 = float4{0.f, 0.f, 0.f, 0.f};

  for (int c = tid; c < 128 * 16; c += 256) {
    int row = c >> 4, kc = c & 15;
    *(bf16x8*)(&sB[swz_idx(row, kc)]) = *(const bf16x8*)(Wbf + (long)row * 128 + kc * 8);
  }
  float bv[8];
  #pragma unroll
  for (int nt = 0; nt < 8; ++nt) bv[nt] = bias[nt * 16 + l15];

  float4 p0 = z4, p1 = z4, p2 = z4, p3 = z4, p4 = z4, p5 = z4, p6 = z4, p7 = z4;
  {
    long row0 = (long)blockIdx.x * 64;
    bool v0 = row0 + r0 < rows, v1 = row0 + r0 + 16 < rows;
    bool v2 = row0 + r0 + 32 < rows, v3 = row0 + r0 + 48 < rows;
    const float4* s0 = (const float4*)(x + (row0 + r0) * 128 + kc0 * 8);
    const float4* s1 = (const float4*)(x + (row0 + r0 + 16) * 128 + kc0 * 8);
    const float4* s2 = (const float4*)(x + (row0 + r0 + 32) * 128 + kc0 * 8);
    const float4* s3 = (const float4*)(x + (row0 + r0 + 48) * 128 + kc0 * 8);
    if (v0) { p0 = s0[0]; p1 = s0[1]; }
    if (v1) { p2 = s1[0]; p3 = s1[1]; }
    if (v2) { p4 = s2[0]; p5 = s2[1]; }
    if (v3) { p6 = s3[0]; p7 = s3[1]; }
  }

  for (int tile = blockIdx.x; tile < ntiles; tile += gridDim.x) {
    const long row0 = (long)tile * 64;
    *(bf16x8*)(&sA[swz_idx(r0, kc0)]) = cvt8(p0, p1);
    *(bf16x8*)(&sA[swz_idx(r0 + 16, kc0)]) = cvt8(p2, p3);
    *(bf16x8*)(&sA[swz_idx(r0 + 32, kc0)]) = cvt8(p4, p5);
    *(bf16x8*)(&sA[swz_idx(r0 + 48, kc0)]) = cvt8(p6, p7);
    if (tid < 66) {
      long idx = row0 - 1 + tid;
      sBatchE[tid] = (idx < 0) ? -3 : (idx < rows ? batch[idx] : -2);
    }
    __syncthreads();

    float4 n0 = z4, n1 = z4, n2 = z4, n3 = z4, n4 = z4, n5 = z4, n6 = z4, n7 = z4;
    {
      int next = tile + gridDim.x;
      if (next < ntiles) {
        long rn = (long)next * 64;
        bool v0 = rn + r0 < rows, v1 = rn + r0 + 16 < rows;
        bool v2 = rn + r0 + 32 < rows, v3 = rn + r0 + 48 < rows;
        const float4* s0 = (const float4*)(x + (rn + r0) * 128 + kc0 * 8);
        const float4* s1 = (const float4*)(x + (rn + r0 + 16) * 128 + kc0 * 8);
        const float4* s2 = (const float4*)(x + (rn + r0 + 32) * 128 + kc0 * 8);
        const float4* s3 = (const float4*)(x + (rn + r0 + 48) * 128 + kc0 * 8);
        if (v0) { n0 = s0[0]; n1 = s0[1]; }
        if (v1) { n2 = s1[0]; n3 = s1[1]; }
        if (v2) { n4 = s2[0]; n5 = s2[1]; }
        if (v3) { n6 = s3[0]; n7 = s3[1]; }
      }
    }

    f32x4 acc[8];
    #pragma unroll
    for (int nt = 0; nt < 8; ++nt) acc[nt] = f32x4{0.f, 0.f, 0.f, 0.f};
    const int mrow = wv * 16 + l15;
    #pragma unroll
    for (int ks = 0; ks < 4; ++ks) {
      bf16x8 af = *(const bf16x8*)(&sA[swz_idx(mrow, ks * 4 + kg)]);
      #pragma unroll
      for (int nt = 0; nt < 8; ++nt) {
        bf16x8 bfr = *(const bf16x8*)(&sB[swz_idx(nt * 16 + l15, ks * 4 + kg)]);
        acc[nt] = __builtin_amdgcn_mfma_f32_16x16x32_bf16(af, bfr, acc[nt], 0, 0, 0);
      }
    }

    // band pool (wave-uniform segment walk, exclusive stores)
    {
      const int rbeg = wv * 16;
      const long band = (long)tile * 4 + wv;
      int r = 0;
      while (r < 16) {
        int g = sBatchE[1 + rbeg + r];
        if (g < 0) break;
        int e = r + 1;
        while (e < 16 && sBatchE[1 + rbeg + e] == g) ++e;
        float s8[8];
        #pragma unroll
        for (int q = 0; q < 8; ++q) s8[q] = 0.f;
        #pragma unroll
        for (int j = 0; j < 4; ++j) {
          int row = kg + 4 * j;
          if (row >= r && row < e) {
            bf16x8 v = *(const bf16x8*)(&sA[swz_idx(rbeg + row, l15)]);
            #pragma unroll
            for (int q = 0; q < 8; ++q) s8[q] += (float)v[q];
          }
        }
        #pragma unroll
        for (int q = 0; q < 8; ++q) {
          s8[q] += __shfl_xor(s8[q], 16, 64);
          s8[q] += __shfl_xor(s8[q], 32, 64);
        }
        bool lext = (r == 0) && (sBatchE[rbeg] == g);
        bool rext = (e == 16) && (sBatchE[1 + rbeg + 16] == g);
        if (kg == 0) {
          float* dst = (!lext && !rext)
              ? (pool + (long)g * 128)
              : (edgebuf + (band * 2 + ((r == 0) ? 0 : 1)) * 128);
          *(float4*)(dst + l15 * 8) = float4{s8[0], s8[1], s8[2], s8[3]};
          *(float4*)(dst + l15 * 8 + 4) = float4{s8[4], s8[5], s8[6], s8[7]};
        }
        r = e;
      }
    }

    // epilogue: bounce through own band of sA, coalesced b128 stores
    #pragma unroll
    for (int nt = 0; nt < 8; ++nt) {
      int col = nt * 16 + l15;
      #pragma unroll
      for (int j = 0; j < 4; ++j) {
        int brow = wv * 16 + kg * 4 + j;
        __bf16 hb = (__bf16)(acc[nt][j] + bv[nt]);
        sA[brow * 128 + col] = __builtin_bit_cast(ushort, hb);
      }
    }
    #pragma unroll
    for (int t = 0; t < 4; ++t) {
      int g = t * 64 + lane;
      int brow = g >> 4, chunk = g & 15;
      long grow = row0 + wv * 16 + brow;
      if (grow < rows) {
        bf16x8 v = *(const bf16x8*)(&sA[(wv * 16 + brow) * 128 + chunk * 8]);
        *(bf16x8*)(xl + grow * 128 + chunk * 8) = v;
      }
    }
    __syncthreads();
    p0 = n0; p1 = n1; p2 = n2; p3 = n3; p4 = n4; p5 = n5; p6 = n6; p7 = n7;
  }
}

// ---- pool combine: cb0[g] = bf16(relu(direct or sum of edge slots)). Wave per graph. ----
__global__ __launch_bounds__(256) void k_poolfix(const int* __restrict__ seg,
                                                 const float* __restrict__ edgebuf,
                                                 const float* __restrict__ pool,
                                                 __bf16* __restrict__ out0, int G) {
  int wid = (blockIdx.x << 2) + (threadIdx.x >> 6);
  if (wid >= G) return;
  int lane = threadIdx.x & 63;
  int s = seg[wid], e = seg[wid + 1];
  float vx = 0.f, vy = 0.f;
  if (s < e) {
    int b0 = s >> 4, b1 = (e - 1) >> 4;
    if (b0 == b1) {
      float2 u = *(const float2*)(pool + (long)wid * 128 + lane * 2);
      vx = u.x; vy = u.y;
    } else {
      for (int t = b0; t <= b1; ++t) {
        int slot = (t == b0 && (s > (t << 4))) ? 1 : 0;
        const float* src = edgebuf + ((long)t * 2 + slot) * 128;
        float2 u = *(const float2*)(src + lane * 2);
        vx += u.x; vy += u.y;
      }
    }
  }
  __bf16 hx = (__bf16)fmaxf(vx, 0.f);
  __bf16 hy = (__bf16)fmaxf(vy, 0.f);
  ushort2 st{__builtin_bit_cast(ushort, hx), __builtin_bit_cast(ushort, hy)};
  *(ushort2*)((ushort*)out0 + (long)wid * 128 + lane * 2) = st;
}

// ---- small GEMM (bf16 A): out[r,c] = bias[c] + sum_k A[r,k]*W[c,k], fp32 out ----
__global__ __launch_bounds__(256) void k_gemm128b(const __bf16* __restrict__ A,
                                                  const __bf16* __restrict__ W,
                                                  const float* __restrict__ bias,
                                                  float* __restrict__ out,
                                                  int rows) {
  __shared__ __align__(16) ushort sB[128 * 128];
  __shared__ __align__(16) ushort sA[64 * 128];
  const int tid = threadIdx.x;
  const long row0 = (long)blockIdx.x * 64;
  for (int c = tid; c < 128 * 16; c += 256) {
    int row = c >> 4, kc = c & 15;
    *(bf16x8*)(&sB[swz_idx(row, kc)]) = *(const bf16x8*)(W + (long)row * 128 + kc * 8);
  }
  for (int c = tid; c < 64 * 16; c += 256) {
    int r = c >> 4, kc = c & 15;
    long gr = row0 + r;
    bf16x8 v;
    if (gr < rows) {
      v = *(const bf16x8*)(A + gr * 128 + kc * 8);
    } else {
      #pragma unroll
      for (int q = 0; q < 8; ++q) v[q] = (__bf16)0.f;
    }
    *(bf16x8*)(&sA[swz_idx(r, kc)]) = v;
  }
  const int lane = tid & 63;
  const int wv = tid >> 6;
  const int l15 = lane & 15;
  const int kg = lane >> 4;
  __syncthreads();

  f32x4 acc[8];
  #pragma unroll
  for (int nt = 0; nt < 8; ++nt) acc[nt] = f32x4{0.f, 0.f, 0.f, 0.f};
  const int mrow = wv * 16 + l15;
  #pragma unroll
  for (int ks = 0; ks < 4; ++ks) {
    bf16x8 af = *(const bf16x8*)(&sA[swz_idx(mrow, ks * 4 + kg)]);
    #pragma unroll
    for (int nt = 0; nt < 8; ++nt) {
      bf16x8 bfr = *(const bf16x8*)(&sB[swz_idx(nt * 16 + l15, ks * 4 + kg)]);
      acc[nt] = __builtin_amdgcn_mfma_f32_16x16x32_bf16(af, bfr, acc[nt], 0, 0, 0);
    }
  }
  #pragma unroll
  for (int nt = 0; nt < 8; ++nt) {
    int col = nt * 16 + l15;
    float bvv = bias[col];
    #pragma unroll
    for (int j = 0; j < 4; ++j) {
      long r = row0 + wv * 16 + kg * 4 + j;
      if (r < rows) out[r * 128 + col] = acc[nt][j] + bvv;
    }
  }
}

// ---- fused GATv2: 8 rows per iteration (dual independent rows), online softmax ----
__global__ __launch_bounds__(256) void k_gat(const __bf16* __restrict__ xl,
                                             const float* __restrict__ xr,
                                             const int* __restrict__ seg,
                                             const float* __restrict__ att,
                                             const float* __restrict__ gat_bias,
                                             float* __restrict__ h, int G) {
  int wid = (blockIdx.x << 2) + (threadIdx.x >> 6);
  if (wid >= G) return;
  int lane = threadIdx.x & 63;
  int grp = lane >> 4, li = lane & 15;
  int s = seg[wid], e = seg[wid + 1];
  int d0 = li * 8;

  const float* xrp = xr + (long)wid * G_DIM + d0;
  float xrv[8], atv[8];
  {
    float4 a0 = *(const float4*)(xrp);
    float4 a1 = *(const float4*)(xrp + 4);
    float4 t0 = *(const float4*)(att + d0);
    float4 t1 = *(const float4*)(att + d0 + 4);
    xrv[0]=a0.x; xrv[1]=a0.y; xrv[2]=a0.z; xrv[3]=a0.w;
    xrv[4]=a1.x; xrv[5]=a1.y; xrv[6]=a1.z; xrv[7]=a1.w;
    atv[0]=t0.x; atv[1]=t0.y; atv[2]=t0.z; atv[3]=t0.w;
    atv[4]=t1.x; atv[5]=t1.y; atv[6]=t1.z; atv[7]=t1.w;
  }

  float m = -1e30f, den = 0.f;
  float acc[8];
  #pragma unroll
  for (int q = 0; q < 8; ++q) acc[q] = 0.f;

  for (int base = s; base < e; base += 8) {
    int iA = base + grp;
    int iB = iA + 4;
    bool vA = iA < e, vB = iB < e;
    float xvA[8], xvB[8];
    if (vA) {
      bf16x8 v = *(const bf16x8*)((const ushort*)xl + (long)iA * G_DIM + d0);
      #pragma unroll
      for (int q = 0; q < 8; ++q) xvA[q] = (float)v[q];
    } else {
      #pragma unroll
      for (int q = 0; q < 8; ++q) xvA[q] = 0.f;
    }
    if (vB) {
      bf16x8 v = *(const bf16x8*)((const ushort*)xl + (long)iB * G_DIM + d0);
      #pragma unroll
      for (int q = 0; q < 8; ++q) xvB[q] = (float)v[q];
    } else {
      #pragma unroll
      for (int q = 0; q < 8; ++q) xvB[q] = 0.f;
    }
    float pA = 0.f, pB = 0.f;
    #pragma unroll
    for (int q = 0; q < 8; ++q) {
      float tA = xvA[q] + xrv[q];
      float tB = xvB[q] + xrv[q];
      tA = fmaxf(tA, 0.f) + 0.01f * fminf(tA, 0.f);
      tB = fmaxf(tB, 0.f) + 0.01f * fminf(tB, 0.f);
      pA = fmaf(tA, atv[q], pA);
      pB = fmaf(tB, atv[q], pB);
    }
    #pragma unroll
    for (int off = 1; off <= 8; off <<= 1) {
      pA += __shfl_xor(pA, off, 64);
      pB += __shfl_xor(pB, off, 64);
    }
    float peA = vA ? pA : -1e30f;
    float peB = vB ? pB : -1e30f;
    float a1 = __shfl_xor(peA, 16, 64);
    float a2 = __shfl_xor(peA, 32, 64);
    float a3 = __shfl_xor(a1, 32, 64);
    float b1 = __shfl_xor(peB, 16, 64);
    float b2 = __shfl_xor(peB, 32, 64);
    float b3 = __shfl_xor(b1, 32, 64);
    float mx = fmaxf(fmaxf(fmaxf(peA, a1), fmaxf(a2, a3)),
                     fmaxf(fmaxf(peB, b1), fmaxf(b2, b3)));
    float nm = fmaxf(m, mx);
    float sc = __expf(m - nm);
    float wA = __expf(peA - nm);
    float wB = __expf(peB - nm);
    den = den * sc + wA + wB
        + __expf(a1 - nm) + __expf(a2 - nm) + __expf(a3 - nm)
        + __expf(b1 - nm) + __expf(b2 - nm) + __expf(b3 - nm);
    #pragma unroll
    for (int q = 0; q < 8; ++q) acc[q] = acc[q] * sc + wA * xvA[q] + wB * xvB[q];
    m = nm;
  }
  #pragma unroll
  for (int q = 0; q < 8; ++q) {
    acc[q] += __shfl_xor(acc[q], 16, 64);
    acc[q] += __shfl_xor(acc[q], 32, 64);
  }
  if (grp == 0) {
    float inv = (e > s) ? 1.f / den : 0.f;
    float o[8];
    #pragma unroll
    for (int q = 0; q < 8; ++q) {
      float v = acc[q] * inv + gat_bias[d0 + q];
      o[q] = v > 0.f ? v : __expf(v) - 1.f;  // elu
    }
    float* dst = h + (long)wid * G_DIM + d0;
    *(float4*)(dst) = float4{o[0], o[1], o[2], o[3]};
    *(float4*)(dst + 4) = float4{o[4], o[5], o[6], o[7]};
  }
}

// ---- fused GRU + next-xr GEMM: gates via ping-pong W staging; after gate math,
// nxt bounces through LDS into A-fragment layout and one more MFMA pass computes
// xrdst = nxt @ Wnext.T + bnext (Wr for t<2, Wfc for t=2 -> final output). ----
__global__ __launch_bounds__(256) void k_grufuse(const float* __restrict__ h,
                                                 const __bf16* __restrict__ cur,
                                                 const __bf16* __restrict__ W_ih,
                                                 const __bf16* __restrict__ W_hh,
                                                 const float* __restrict__ b_ih,
                                                 const float* __restrict__ b_hh,
                                                 const __bf16* __restrict__ Wnext,
                                                 const float* __restrict__ bnext,
                                                 __bf16* __restrict__ nxt,
                                                 float* __restrict__ xrdst,
                                                 int G, int writeNxt) {
  __shared__ __align__(16) ushort sA1[64 * 128];     // h tile (swz) -> nxt A-fragments (swz)
  __shared__ __align__(16) ushort sA2[64 * 128];     // cur tile (swz) -> nxt linear bounce
  __shared__ __align__(16) ushort sW[2][128 * 128];  // ping-pong gate/W-next buffers (64 KB)
  const int tid = threadIdx.x;
  const int lane = tid & 63, wv = tid >> 6, l15 = lane & 15, kg = lane >> 4;
  const long row0 = (long)blockIdx.x * 64;
  const int mrow = wv * 16 + l15;
  const int r0w = tid >> 4, kcw = tid & 15;

  // stage A tiles + first W gate (W_ih g0) into sW[0]
  for (int c = tid; c < 64 * 16; c += 256) {
    int r = c >> 4, kc = c & 15;
    long gr = row0 + r;
    const float4* s1 = (const float4*)(h + gr * 128 + kc * 8);
    *(bf16x8*)(&sA1[swz_idx(r, kc)]) = cvt8(s1[0], s1[1]);
    *(bf16x8*)(&sA2[swz_idx(r, kc)]) = *(const bf16x8*)(cur + gr * 128 + kc * 8);
  }
  {
    const __bf16* wp = W_ih + (long)r0w * 128 + kcw * 8;
    #pragma unroll
    for (int k = 0; k < 8; ++k)
      *(bf16x8*)(&sW[0][swz_idx(r0w + 16 * k, kcw)]) = *(const bf16x8*)(wp + k * 2048);
  }
  __syncthreads();

  f32x4 rp[8], zp[8], inn[8], hnn[8];
  #pragma unroll
  for (int nt = 0; nt < 8; ++nt) {
    rp[nt] = f32x4{0.f, 0.f, 0.f, 0.f};
    zp[nt] = f32x4{0.f, 0.f, 0.f, 0.f};
    inn[nt] = f32x4{0.f, 0.f, 0.f, 0.f};
    hnn[nt] = f32x4{0.f, 0.f, 0.f, 0.f};
  }

#define MM(ACC, SAX, WB)                                                      \
  _Pragma("unroll") for (int ks = 0; ks < 4; ++ks) {                          \
    bf16x8 af = *(const bf16x8*)(&SAX[swz_idx(mrow, ks * 4 + kg)]);           \
    _Pragma("unroll") for (int nt = 0; nt < 8; ++nt) {                        \
      bf16x8 bfr = *(const bf16x8*)(&(WB)[swz_idx(nt * 16 + l15, ks * 4 + kg)]); \
      ACC[nt] = __builtin_amdgcn_mfma_f32_16x16x32_bf16(af, bfr, ACC[nt], 0, 0, 0); \
    }                                                                         \
  }

#define STEP(S, NEXTSRC, ACC, SAX)                                            \
  {                                                                           \
    bf16x8 w0, w1, w2, w3, w4, w5, w6, w7;                                    \
    {                                                                         \
      const __bf16* wp = (NEXTSRC) + (long)r0w * 128 + kcw * 8;               \
      w0 = *(const bf16x8*)(wp + 0 * 2048); w1 = *(const bf16x8*)(wp + 1 * 2048); \
      w2 = *(const bf16x8*)(wp + 2 * 2048); w3 = *(const bf16x8*)(wp + 3 * 2048); \
      w4 = *(const bf16x8*)(wp + 4 * 2048); w5 = *(const bf16x8*)(wp + 5 * 2048); \
      w6 = *(const bf16x8*)(wp + 6 * 2048); w7 = *(const bf16x8*)(wp + 7 * 2048); \
    }                                                                         \
    MM(ACC, SAX, sW[(S) & 1])                                                 \
    {                                                                         \
      ushort* wb = sW[((S) + 1) & 1];                                         \
      *(bf16x8*)(&wb[swz_idx(r0w + 0, kcw)])   = w0;                          \
      *(bf16x8*)(&wb[swz_idx(r0w + 16, kcw)])  = w1;                          \
      *(bf16x8*)(&wb[swz_idx(r0w + 32, kcw)])  = w2;                          \
      *(bf16x8*)(&wb[swz_idx(r0w + 48, kcw)])  = w3;                          \
      *(bf16x8*)(&wb[swz_idx(r0w + 64, kcw)])  = w4;                          \
      *(bf16x8*)(&wb[swz_idx(r0w + 80, kcw)])  = w5;                          \
      *(bf16x8*)(&wb[swz_idx(r0w + 96, kcw)])  = w6;                          \
      *(bf16x8*)(&wb[swz_idx(r0w + 112, kcw)]) = w7;                          \
    }                                                                         \
    __syncthreads();                                                          \
  }

  STEP(0, W_hh,          rp,  sA1)
  STEP(1, W_ih + 16384,  rp,  sA2)
  STEP(2, W_hh + 16384,  zp,  sA1)
  STEP(3, W_ih + 32768,  zp,  sA2)
  STEP(4, W_hh + 32768,  inn, sA1)
  STEP(5, Wnext,         hnn, sA2)   // prefetch Wnext into sW[0]
#undef STEP

  // gate math -> nv (reads hp from sA2 BEFORE overwriting it)
  float nv[8][4];
  #pragma unroll
  for (int nt = 0; nt < 8; ++nt) {
    int col = nt * 16 + l15;
    float bir = b_ih[col], biz = b_ih[col + 128], bin = b_ih[col + 256];
    float bhr = b_hh[col], bhz = b_hh[col + 128], bhn = b_hh[col + 256];
    #pragma unroll
    for (int j = 0; j < 4; ++j) {
      int row = wv * 16 + kg * 4 + j;
      float hp = bf2f(sA2[swz_idx(row, col >> 3) + (col & 7)]);
      float rr = 1.f / (1.f + __expf(-(rp[nt][j] + bir + bhr)));
      float zz = 1.f / (1.f + __expf(-(zp[nt][j] + biz + bhz)));
      float nn = tanhf(inn[nt][j] + bin + rr * (hnn[nt][j] + bhn));
      nv[nt][j] = fmaxf((1.f - zz) * nn + zz * hp, 0.f);
    }
  }
  // write nxt: swz into sA1 (A-fragments, own band) + linear into sA2 (store bounce)
  #pragma unroll
  for (int nt = 0; nt < 8; ++nt) {
    int col = nt * 16 + l15;
    #pragma unroll
    for (int j = 0; j < 4; ++j) {
      int row = wv * 16 + kg * 4 + j;
      ushort hb = __builtin_bit_cast(ushort, (__bf16)nv[nt][j]);
      sA1[swz_idx(row, col >> 3) + (col & 7)] = hb;
      sA2[row * 128 + col] = hb;
    }
  }
  // xr = nxt @ Wnext.T + bnext  (sA1 reads are wave-local -> no barrier needed)
  f32x4 acc2[8];
  #pragma unroll
  for (int nt = 0; nt < 8; ++nt) acc2[nt] = f32x4{0.f, 0.f, 0.f, 0.f};
  MM(acc2, sA1, sW[0])
#undef MM
  #pragma unroll
  for (int nt = 0; nt < 8; ++nt) {
    int col = nt * 16 + l15;
    float bn = bnext[col];
    #pragma unroll
    for (int j = 0; j < 4; ++j) {
      long r = row0 + wv * 16 + kg * 4 + j;
      if (r < G) xrdst[r * 128 + col] = acc2[nt][j] + bn;
    }
  }
  if (writeNxt) {
    #pragma unroll
    for (int t = 0; t < 4; ++t) {
      int g = t * 64 + lane;
      int brow = g >> 4, chunk = g & 15;
      long grow = row0 + wv * 16 + brow;
      if (grow < G) {
        bf16x8 v = *(const bf16x8*)(&sA2[(wv * 16 + brow) * 128 + chunk * 8]);
        *(bf16x8*)(nxt + grow * 128 + chunk * 8) = v;
      }
    }
  }
}

extern "C" void kernel_launch(void* const* d_in, const int* in_sizes, int n_in,
                              void* d_out, int out_size, void* d_ws, size_t ws_size,
                              hipStream_t stream) {
  const float* x        = (const float*)d_in[0];
  const int*   batch    = (const int*)d_in[1];
  const float* Wl       = (const float*)d_in[2];
  const float* bl       = (const float*)d_in[3];
  const float* Wr       = (const float*)d_in[4];
  const float* br       = (const float*)d_in[5];
  const float* att      = (const float*)d_in[6];
  const float* gat_bias = (const float*)d_in[7];
  const float* W_ih     = (const float*)d_in[8];
  const float* W_hh     = (const float*)d_in[9];
  const float* b_ih     = (const float*)d_in[10];
  const float* b_hh     = (const float*)d_in[11];
  const float* Wfc      = (const float*)d_in[12];
  const float* bfc      = (const float*)d_in[13];
  const int N = in_sizes[1];
  const int G = out_size / G_DIM;
  float* outf = (float*)d_out;

  const int ntiles_big = (N + 63) / 64;
  const long nbands = (long)ntiles_big * 4;

  char* ws = (char*)d_ws;
  size_t off = 0;
  auto alloc = [&](size_t bytes) -> void* {
    void* p = ws + off;
    off = (off + bytes + 255) & ~(size_t)255;
    return p;
  };
  int*    seg      = (int*)alloc(((size_t)G + 1) * sizeof(int));
  float*  poolpart = (float*)alloc((size_t)G * G_DIM * sizeof(float));
  float*  xr       = (float*)alloc((size_t)G * G_DIM * sizeof(float));
  float*  hbuf     = (float*)alloc((size_t)G * G_DIM * sizeof(float));
  __bf16* cb0      = (__bf16*)alloc((size_t)G * G_DIM * sizeof(ushort));
  __bf16* cb1      = (__bf16*)alloc((size_t)G * G_DIM * sizeof(ushort));
  __bf16* wsW      = (__bf16*)alloc((size_t)147456 * sizeof(ushort));
  float*  edgebuf  = (float*)alloc((size_t)nbands * 2 * G_DIM * sizeof(float));
  __bf16* xl       = (__bf16*)alloc((size_t)N * G_DIM * sizeof(ushort));
  (void)ws_size; (void)n_in;

  __bf16* Wlb  = wsW;
  __bf16* Wrb  = wsW + 16384;
  __bf16* Wihb = wsW + 32768;
  __bf16* Whhb = wsW + 81920;
  __bf16* Wfcb = wsW + 131072;

  k_wcvt<<<(147456 / 8 + 255) / 256, 256, 0, stream>>>(Wl, Wr, W_ih, W_hh, Wfc, wsW);
  k_seg<<<(N + 255) / 256, 256, 0, stream>>>(batch, seg, N, G);

  k_xlgemm<<<768, 256, 0, stream>>>(Wlb, x, bl, batch, xl, poolpart, edgebuf, N, ntiles_big);
  k_poolfix<<<(G + 3) / 4, 256, 0, stream>>>(seg, edgebuf, poolpart, cb0, G);

  const int ntiles_g = (G + 63) / 64;
  k_gemm128b<<<ntiles_g, 256, 0, stream>>>(cb0, Wrb, br, xr, G);

  // t=0
  k_gat<<<(G + 3) / 4, 256, 0, stream>>>(xl, xr, seg, att, gat_bias, hbuf, G);
  k_grufuse<<<ntiles_g, 256, 0, stream>>>(hbuf, cb0, Wihb, Whhb, b_ih, b_hh,
                                          Wrb, br, cb1, xr, G, 1);
  // t=1
  k_gat<<<(G + 3) / 4, 256, 0, stream>>>(xl, xr, seg, att, gat_bias, hbuf, G);
  k_grufuse<<<ntiles_g, 256, 0, stream>>>(hbuf, cb1, Wihb, Whhb, b_ih, b_hh,
                                          Wrb, br, cb0, xr, G, 1);
  // t=2: Wnext = Wfc, write final output directly
  k_gat<<<(G + 3) / 4, 256, 0, stream>>>(xl, xr, seg, att, gat_bias, hbuf, G);
  k_grufuse<<<ntiles_g, 256, 0, stream>>>(hbuf, cb0, Wihb, Whhb, b_ih, b_hh,
                                          Wfcb, bfc, cb1, outf, G, 0);
}

// Round 8
// 249.156 us; speedup vs baseline: 3.5641x; 1.0747x over previous
//
#include <hip/hip_runtime.h>
#include <hip/hip_bf16.h>

typedef __bf16 bf16x8 __attribute__((ext_vector_type(8)));
typedef float f32x4 __attribute__((ext_vector_type(4)));

#define G_DIM 128

// ---- helpers ----
__device__ __forceinline__ float bf2f(ushort u) {
  return __uint_as_float(((unsigned int)u) << 16);
}

__device__ __forceinline__ bf16x8 cvt8(float4 f0, float4 f1) {
  bf16x8 v;
  v[0] = (__bf16)f0.x; v[1] = (__bf16)f0.y; v[2] = (__bf16)f0.z; v[3] = (__bf16)f0.w;
  v[4] = (__bf16)f1.x; v[5] = (__bf16)f1.y; v[6] = (__bf16)f1.z; v[7] = (__bf16)f1.w;
  return v;
}

// swizzled ushort index into a row-major [rows][128] bf16 LDS tile.
__device__ __forceinline__ int swz_idx(int row, int kc) {
  return (row * 128 + kc * 8) ^ ((row & 7) << 3);
}

// ---- merged init: W fp32->bf16 pack (blocks 0..71) + segment ranges (blocks 72..) ----
// wsW layout (elem offsets): Wl@0, Wr@16384, W_ih@32768, W_hh@81920, Wfc@131072
#define WCVT_BLOCKS 72
__global__ void k_init(const float* __restrict__ Wl, const float* __restrict__ Wr,
                       const float* __restrict__ Wih, const float* __restrict__ Whh,
                       const float* __restrict__ Wfc, __bf16* __restrict__ dst,
                       const int* __restrict__ batch, int* __restrict__ seg,
                       int n, int g) {
  if (blockIdx.x < WCVT_BLOCKS) {
    int i = blockIdx.x * blockDim.x + threadIdx.x;
    if (i >= 147456 / 8) return;
    int e = i * 8;
    const float* src; int off;
    if (e < 16384)       { src = Wl;  off = e; }
    else if (e < 32768)  { src = Wr;  off = e - 16384; }
    else if (e < 81920)  { src = Wih; off = e - 32768; }
    else if (e < 131072) { src = Whh; off = e - 81920; }
    else                 { src = Wfc; off = e - 131072; }
    float4 a = ((const float4*)(src + off))[0];
    float4 b = ((const float4*)(src + off))[1];
    *(bf16x8*)(dst + e) = cvt8(a, b);
  } else {
    int i = (blockIdx.x - WCVT_BLOCKS) * blockDim.x + threadIdx.x;
    if (i >= n) return;
    int b = batch[i];
    int prev = (i == 0) ? -1 : batch[i - 1];
    for (int q = prev + 1; q <= b; ++q) seg[q] = i;
    if (i == n - 1) {
      for (int q = b + 1; q <= g; ++q) seg[q] = n;
    }
  }
}

// ---- fused GEMM + band pool: xl = bf16(x @ Wl.T + bl); per-band segment sums.
// Band = 16-row slice (one wave). Interior segments -> exclusive pool[g] store.
// Band-edge segments -> edgebuf[band][slot]. NO atomics anywhere. (unchanged from R7)
__global__ __launch_bounds__(256, 3) void k_xlgemm(const __bf16* __restrict__ Wbf,
                                                   const float* __restrict__ x,
                                                   const float* __restrict__ bias,
                                                   const int* __restrict__ batch,
                                                   __bf16* __restrict__ xl,
                                                   float* __restrict__ pool,
                                                   float* __restrict__ edgebuf,
                                                   int rows, int ntiles) {
  __shared__ __align__(16) ushort sB[128 * 128];  // W, swizzled, persistent
  __shared__ __align__(16) ushort sA[64 * 128];   // x tile (swz) -> reused as xl tile (linear)
  __shared__ int sBatchE[66];                     // batch[row0-1 .. row0+64]
  const int tid = threadIdx.x;
  const int lane = tid & 63;
  const int wv = tid >> 6;
  const int l15 = lane & 15;
  const int kg = lane >> 4;
  const int r0 = tid >> 4, kc0 = tid & 15;
  const float4 z4 = float4{0.f, 0.f, 0.f, 0.f};

  for (int c = tid; c < 128 * 16; c += 256) {
    int row = c >> 4, kc = c & 15;
    *(bf16x8*)(&sB[swz_idx(row, kc)]) = *(const bf16x8*)(Wbf + (long)row * 128 + kc * 8);
  }
  float bv[8];
  #pragma unroll
  for (int nt = 0; nt < 8; ++nt) bv[nt] = bias[nt * 16 + l15];

  float4 p0 = z4, p1 = z4, p2 = z4, p3 = z4, p4 = z4, p5 = z4, p6 = z4, p7 = z4;
  {
    long row0 = (long)blockIdx.x * 64;
    bool v0 = row0 + r0 < rows, v1 = row0 + r0 + 16 < rows;
    bool v2 = row0 + r0 + 32 < rows, v3 = row0 + r0 + 48 < rows;
    const float4* s0 = (const float4*)(x + (row0 + r0) * 128 + kc0 * 8);
    const float4* s1 = (const float4*)(x + (row0 + r0 + 16) * 128 + kc0 * 8);
    const float4* s2 = (const float4*)(x + (row0 + r0 + 32) * 128 + kc0 * 8);
    const float4* s3 = (const float4*)(x + (row0 + r0 + 48) * 128 + kc0 * 8);
    if (v0) { p0 = s0[0]; p1 = s0[1]; }
    if (v1) { p2 = s1[0]; p3 = s1[1]; }
    if (v2) { p4 = s2[0]; p5 = s2[1]; }
    if (v3) { p6 = s3[0]; p7 = s3[1]; }
  }

  for (int tile = blockIdx.x; tile < ntiles; tile += gridDim.x) {
    const long row0 = (long)tile * 64;
    *(bf16x8*)(&sA[swz_idx(r0, kc0)]) = cvt8(p0, p1);
    *(bf16x8*)(&sA[swz_idx(r0 + 16, kc0)]) = cvt8(p2, p3);
    *(bf16x8*)(&sA[swz_idx(r0 + 32, kc0)]) = cvt8(p4, p5);
    *(bf16x8*)(&sA[swz_idx(r0 + 48, kc0)]) = cvt8(p6, p7);
    if (tid < 66) {
      long idx = row0 - 1 + tid;
      sBatchE[tid] = (idx < 0) ? -3 : (idx < rows ? batch[idx] : -2);
    }
    __syncthreads();

    float4 n0 = z4, n1 = z4, n2 = z4, n3 = z4, n4 = z4, n5 = z4, n6 = z4, n7 = z4;
    {
      int next = tile + gridDim.x;
      if (next < ntiles) {
        long rn = (long)next * 64;
        bool v0 = rn + r0 < rows, v1 = rn + r0 + 16 < rows;
        bool v2 = rn + r0 + 32 < rows, v3 = rn + r0 + 48 < rows;
        const float4* s0 = (const float4*)(x + (rn + r0) * 128 + kc0 * 8);
        const float4* s1 = (const float4*)(x + (rn + r0 + 16) * 128 + kc0 * 8);
        const float4* s2 = (const float4*)(x + (rn + r0 + 32) * 128 + kc0 * 8);
        const float4* s3 = (const float4*)(x + (rn + r0 + 48) * 128 + kc0 * 8);
        if (v0) { n0 = s0[0]; n1 = s0[1]; }
        if (v1) { n2 = s1[0]; n3 = s1[1]; }
        if (v2) { n4 = s2[0]; n5 = s2[1]; }
        if (v3) { n6 = s3[0]; n7 = s3[1]; }
      }
    }

    f32x4 acc[8];
    #pragma unroll
    for (int nt = 0; nt < 8; ++nt) acc[nt] = f32x4{0.f, 0.f, 0.f, 0.f};
    const int mrow = wv * 16 + l15;
    #pragma unroll
    for (int ks = 0; ks < 4; ++ks) {
      bf16x8 af = *(const bf16x8*)(&sA[swz_idx(mrow, ks * 4 + kg)]);
      #pragma unroll
      for (int nt = 0; nt < 8; ++nt) {
        bf16x8 bfr = *(const bf16x8*)(&sB[swz_idx(nt * 16 + l15, ks * 4 + kg)]);
        acc[nt] = __builtin_amdgcn_mfma_f32_16x16x32_bf16(af, bfr, acc[nt], 0, 0, 0);
      }
    }

    // band pool (wave-uniform segment walk, exclusive stores)
    {
      const int rbeg = wv * 16;
      const long band = (long)tile * 4 + wv;
      int r = 0;
      while (r < 16) {
        int g = sBatchE[1 + rbeg + r];
        if (g < 0) break;
        int e = r + 1;
        while (e < 16 && sBatchE[1 + rbeg + e] == g) ++e;
        float s8[8];
        #pragma unroll
        for (int q = 0; q < 8; ++q) s8[q] = 0.f;
        #pragma unroll
        for (int j = 0; j < 4; ++j) {
          int row = kg + 4 * j;
          if (row >= r && row < e) {
            bf16x8 v = *(const bf16x8*)(&sA[swz_idx(rbeg + row, l15)]);
            #pragma unroll
            for (int q = 0; q < 8; ++q) s8[q] += (float)v[q];
          }
        }
        #pragma unroll
        for (int q = 0; q < 8; ++q) {
          s8[q] += __shfl_xor(s8[q], 16, 64);
          s8[q] += __shfl_xor(s8[q], 32, 64);
        }
        bool lext = (r == 0) && (sBatchE[rbeg] == g);
        bool rext = (e == 16) && (sBatchE[1 + rbeg + 16] == g);
        if (kg == 0) {
          float* dst = (!lext && !rext)
              ? (pool + (long)g * 128)
              : (edgebuf + (band * 2 + ((r == 0) ? 0 : 1)) * 128);
          *(float4*)(dst + l15 * 8) = float4{s8[0], s8[1], s8[2], s8[3]};
          *(float4*)(dst + l15 * 8 + 4) = float4{s8[4], s8[5], s8[6], s8[7]};
        }
        r = e;
      }
    }

    // epilogue: bounce through own band of sA, coalesced b128 stores
    #pragma unroll
    for (int nt = 0; nt < 8; ++nt) {
      int col = nt * 16 + l15;
      #pragma unroll
      for (int j = 0; j < 4; ++j) {
        int brow = wv * 16 + kg * 4 + j;
        __bf16 hb = (__bf16)(acc[nt][j] + bv[nt]);
        sA[brow * 128 + col] = __builtin_bit_cast(ushort, hb);
      }
    }
    #pragma unroll
    for (int t = 0; t < 4; ++t) {
      int g = t * 64 + lane;
      int brow = g >> 4, chunk = g & 15;
      long grow = row0 + wv * 16 + brow;
      if (grow < rows) {
        bf16x8 v = *(const bf16x8*)(&sA[(wv * 16 + brow) * 128 + chunk * 8]);
        *(bf16x8*)(xl + grow * 128 + chunk * 8) = v;
      }
    }
    __syncthreads();
    p0 = n0; p1 = n1; p2 = n2; p3 = n3; p4 = n4; p5 = n5; p6 = n6; p7 = n7;
  }
}

// ---- fused pool combine + first Wr GEMM: builds pooled rows (relu'd, bf16) directly
// in the LDS A-tile, writes cb0 as side effect, then xr = pool @ Wr.T + br. ----
__global__ __launch_bounds__(256) void k_poolgemm(const int* __restrict__ seg,
                                                  const float* __restrict__ edgebuf,
                                                  const float* __restrict__ poolpart,
                                                  const __bf16* __restrict__ W,
                                                  const float* __restrict__ bias,
                                                  float* __restrict__ xr,
                                                  __bf16* __restrict__ cb0, int G) {
  __shared__ __align__(16) ushort sB[128 * 128];
  __shared__ __align__(16) ushort sA[64 * 128];
  const int tid = threadIdx.x;
  const long g0 = (long)blockIdx.x * 64;
  for (int c = tid; c < 128 * 16; c += 256) {
    int row = c >> 4, kc = c & 15;
    *(bf16x8*)(&sB[swz_idx(row, kc)]) = *(const bf16x8*)(W + (long)row * 128 + kc * 8);
  }
  const int rb = tid >> 4, kc = tid & 15;
  #pragma unroll
  for (int q = 0; q < 4; ++q) {
    int gr = rb + q * 16;
    long g = g0 + gr;
    float f[8];
    #pragma unroll
    for (int u = 0; u < 8; ++u) f[u] = 0.f;
    if (g < G) {
      int s = seg[g], e = seg[g + 1];
      if (s < e) {
        int b0 = s >> 4, b1 = (e - 1) >> 4;
        if (b0 == b1) {
          const float4* src = (const float4*)(poolpart + g * 128 + kc * 8);
          float4 u0 = src[0], u1 = src[1];
          f[0] = u0.x; f[1] = u0.y; f[2] = u0.z; f[3] = u0.w;
          f[4] = u1.x; f[5] = u1.y; f[6] = u1.z; f[7] = u1.w;
        } else {
          for (int t = b0; t <= b1; ++t) {
            int slot = (t == b0 && (s > (t << 4))) ? 1 : 0;
            const float4* src = (const float4*)(edgebuf + ((long)t * 2 + slot) * 128 + kc * 8);
            float4 u0 = src[0], u1 = src[1];
            f[0] += u0.x; f[1] += u0.y; f[2] += u0.z; f[3] += u0.w;
            f[4] += u1.x; f[5] += u1.y; f[6] += u1.z; f[7] += u1.w;
          }
        }
      }
      bf16x8 v;
      #pragma unroll
      for (int u = 0; u < 8; ++u) v[u] = (__bf16)fmaxf(f[u], 0.f);
      *(bf16x8*)(&sA[swz_idx(gr, kc)]) = v;
      *(bf16x8*)(cb0 + g * 128 + kc * 8) = v;
    } else {
      bf16x8 v;
      #pragma unroll
      for (int u = 0; u < 8; ++u) v[u] = (__bf16)0.f;
      *(bf16x8*)(&sA[swz_idx(gr, kc)]) = v;
    }
  }
  const int lane = tid & 63;
  const int wv = tid >> 6;
  const int l15 = lane & 15;
  const int kg = lane >> 4;
  __syncthreads();

  f32x4 acc[8];
  #pragma unroll
  for (int nt = 0; nt < 8; ++nt) acc[nt] = f32x4{0.f, 0.f, 0.f, 0.f};
  const int mrow = wv * 16 + l15;
  #pragma unroll
  for (int ks = 0; ks < 4; ++ks) {
    bf16x8 af = *(const bf16x8*)(&sA[swz_idx(mrow, ks * 4 + kg)]);
    #pragma unroll
    for (int nt = 0; nt < 8; ++nt) {
      bf16x8 bfr = *(const bf16x8*)(&sB[swz_idx(nt * 16 + l15, ks * 4 + kg)]);
      acc[nt] = __builtin_amdgcn_mfma_f32_16x16x32_bf16(af, bfr, acc[nt], 0, 0, 0);
    }
  }
  #pragma unroll
  for (int nt = 0; nt < 8; ++nt) {
    int col = nt * 16 + l15;
    float bvv = bias[col];
    #pragma unroll
    for (int j = 0; j < 4; ++j) {
      long r = g0 + wv * 16 + kg * 4 + j;
      if (r < G) xr[r * 128 + col] = acc[nt][j] + bvv;
    }
  }
}

// ---- fused GATv2: 8 rows per iteration (dual independent rows), online softmax ----
__global__ __launch_bounds__(256) void k_gat(const __bf16* __restrict__ xl,
                                             const float* __restrict__ xr,
                                             const int* __restrict__ seg,
                                             const float* __restrict__ att,
                                             const float* __restrict__ gat_bias,
                                             float* __restrict__ h, int G) {
  int wid = (blockIdx.x << 2) + (threadIdx.x >> 6);
  if (wid >= G) return;
  int lane = threadIdx.x & 63;
  int grp = lane >> 4, li = lane & 15;
  int s = seg[wid], e = seg[wid + 1];
  int d0 = li * 8;

  const float* xrp = xr + (long)wid * G_DIM + d0;
  float xrv[8], atv[8];
  {
    float4 a0 = *(const float4*)(xrp);
    float4 a1 = *(const float4*)(xrp + 4);
    float4 t0 = *(const float4*)(att + d0);
    float4 t1 = *(const float4*)(att + d0 + 4);
    xrv[0]=a0.x; xrv[1]=a0.y; xrv[2]=a0.z; xrv[3]=a0.w;
    xrv[4]=a1.x; xrv[5]=a1.y; xrv[6]=a1.z; xrv[7]=a1.w;
    atv[0]=t0.x; atv[1]=t0.y; atv[2]=t0.z; atv[3]=t0.w;
    atv[4]=t1.x; atv[5]=t1.y; atv[6]=t1.z; atv[7]=t1.w;
  }

  float m = -1e30f, den = 0.f;
  float acc[8];
  #pragma unroll
  for (int q = 0; q < 8; ++q) acc[q] = 0.f;

  for (int base = s; base < e; base += 8) {
    int iA = base + grp;
    int iB = iA + 4;
    bool vA = iA < e, vB = iB < e;
    float xvA[8], xvB[8];
    if (vA) {
      bf16x8 v = *(const bf16x8*)((const ushort*)xl + (long)iA * G_DIM + d0);
      #pragma unroll
      for (int q = 0; q < 8; ++q) xvA[q] = (float)v[q];
    } else {
      #pragma unroll
      for (int q = 0; q < 8; ++q) xvA[q] = 0.f;
    }
    if (vB) {
      bf16x8 v = *(const bf16x8*)((const ushort*)xl + (long)iB * G_DIM + d0);
      #pragma unroll
      for (int q = 0; q < 8; ++q) xvB[q] = (float)v[q];
    } else {
      #pragma unroll
      for (int q = 0; q < 8; ++q) xvB[q] = 0.f;
    }
    float pA = 0.f, pB = 0.f;
    #pragma unroll
    for (int q = 0; q < 8; ++q) {
      float tA = xvA[q] + xrv[q];
      float tB = xvB[q] + xrv[q];
      tA = fmaxf(tA, 0.f) + 0.01f * fminf(tA, 0.f);
      tB = fmaxf(tB, 0.f) + 0.01f * fminf(tB, 0.f);
      pA = fmaf(tA, atv[q], pA);
      pB = fmaf(tB, atv[q], pB);
    }
    #pragma unroll
    for (int off = 1; off <= 8; off <<= 1) {
      pA += __shfl_xor(pA, off, 64);
      pB += __shfl_xor(pB, off, 64);
    }
    float peA = vA ? pA : -1e30f;
    float peB = vB ? pB : -1e30f;
    float a1 = __shfl_xor(peA, 16, 64);
    float a2 = __shfl_xor(peA, 32, 64);
    float a3 = __shfl_xor(a1, 32, 64);
    float b1 = __shfl_xor(peB, 16, 64);
    float b2 = __shfl_xor(peB, 32, 64);
    float b3 = __shfl_xor(b1, 32, 64);
    float mx = fmaxf(fmaxf(fmaxf(peA, a1), fmaxf(a2, a3)),
                     fmaxf(fmaxf(peB, b1), fmaxf(b2, b3)));
    float nm = fmaxf(m, mx);
    float sc = __expf(m - nm);
    float wA = __expf(peA - nm);
    float wB = __expf(peB - nm);
    den = den * sc + wA + wB
        + __expf(a1 - nm) + __expf(a2 - nm) + __expf(a3 - nm)
        + __expf(b1 - nm) + __expf(b2 - nm) + __expf(b3 - nm);
    #pragma unroll
    for (int q = 0; q < 8; ++q) acc[q] = acc[q] * sc + wA * xvA[q] + wB * xvB[q];
    m = nm;
  }
  #pragma unroll
  for (int q = 0; q < 8; ++q) {
    acc[q] += __shfl_xor(acc[q], 16, 64);
    acc[q] += __shfl_xor(acc[q], 32, 64);
  }
  if (grp == 0) {
    float inv = (e > s) ? 1.f / den : 0.f;
    float o[8];
    #pragma unroll
    for (int q = 0; q < 8; ++q) {
      float v = acc[q] * inv + gat_bias[d0 + q];
      o[q] = v > 0.f ? v : __expf(v) - 1.f;  // elu
    }
    float* dst = h + (long)wid * G_DIM + d0;
    *(float4*)(dst) = float4{o[0], o[1], o[2], o[3]};
    *(float4*)(dst + 4) = float4{o[4], o[5], o[6], o[7]};
  }
}

// ---- fused GRU + next-xr GEMM, 32-row tiles (2 blocks/CU): wave owns 32 output
// cols x 32 rows. Ping-pong W staging; hp pre-read to registers; second MFMA pass
// computes xrdst = nxt @ Wnext.T + bnext (Wr for t<2, Wfc for t=2 -> final out). ----
__global__ __launch_bounds__(256) void k_grufuse(const float* __restrict__ h,
                                                 const __bf16* __restrict__ cur,
                                                 const __bf16* __restrict__ W_ih,
                                                 const __bf16* __restrict__ W_hh,
                                                 const float* __restrict__ b_ih,
                                                 const float* __restrict__ b_hh,
                                                 const __bf16* __restrict__ Wnext,
                                                 const float* __restrict__ bnext,
                                                 __bf16* __restrict__ nxt,
                                                 float* __restrict__ xrdst,
                                                 int G, int writeNxt) {
  __shared__ __align__(16) ushort sA1[32 * 128];     // h tile (swz) -> nxt A-frags (swz)
  __shared__ __align__(16) ushort sA2[32 * 128];     // cur tile (swz) -> nxt linear bounce
  __shared__ __align__(16) ushort sW[2][128 * 128];  // ping-pong gate/W-next buffers
  const int tid = threadIdx.x;
  const int lane = tid & 63, wv = tid >> 6, l15 = lane & 15, kg = lane >> 4;
  const long row0 = (long)blockIdx.x * 32;
  const int r0w = tid >> 4, kcw = tid & 15;
  const int colb = wv * 32 + l15;  // + ntl*16

  // stage h (fp32->bf16) and cur (bf16) tiles
  #pragma unroll
  for (int c0 = 0; c0 < 2; ++c0) {
    int c = tid + c0 * 256;
    int r = c >> 4, kc = c & 15;
    long gr = row0 + r;
    bf16x8 v1, v2;
    if (gr < G) {
      const float4* s1 = (const float4*)(h + gr * 128 + kc * 8);
      v1 = cvt8(s1[0], s1[1]);
      v2 = *(const bf16x8*)(cur + gr * 128 + kc * 8);
    } else {
      #pragma unroll
      for (int u = 0; u < 8; ++u) { v1[u] = (__bf16)0.f; v2[u] = (__bf16)0.f; }
    }
    *(bf16x8*)(&sA1[swz_idx(r, kc)]) = v1;
    *(bf16x8*)(&sA2[swz_idx(r, kc)]) = v2;
  }
  // stage W_ih gate0 -> sW[0]
  {
    const __bf16* wp = W_ih + (long)r0w * 128 + kcw * 8;
    #pragma unroll
    for (int k = 0; k < 8; ++k)
      *(bf16x8*)(&sW[0][swz_idx(r0w + 16 * k, kcw)]) = *(const bf16x8*)(wp + k * 2048);
  }
  __syncthreads();

  // pre-read GRU state hp for this thread's output positions (before sA2 overwrite)
  float hp[2][2][4];
  #pragma unroll
  for (int rt = 0; rt < 2; ++rt)
    #pragma unroll
    for (int ntl = 0; ntl < 2; ++ntl) {
      int col = colb + ntl * 16;
      #pragma unroll
      for (int j = 0; j < 4; ++j) {
        int row = rt * 16 + kg * 4 + j;
        hp[rt][ntl][j] = bf2f(sA2[swz_idx(row, col >> 3) + (col & 7)]);
      }
    }

  f32x4 rp[2][2], zp[2][2], inn[2][2], hnn[2][2];
  #pragma unroll
  for (int a = 0; a < 2; ++a)
    #pragma unroll
    for (int b = 0; b < 2; ++b) {
      rp[a][b] = f32x4{0.f, 0.f, 0.f, 0.f};
      zp[a][b] = f32x4{0.f, 0.f, 0.f, 0.f};
      inn[a][b] = f32x4{0.f, 0.f, 0.f, 0.f};
      hnn[a][b] = f32x4{0.f, 0.f, 0.f, 0.f};
    }

#define MM(ACC, SAX, WB)                                                      \
  _Pragma("unroll") for (int ks = 0; ks < 4; ++ks) {                          \
    bf16x8 a0 = *(const bf16x8*)(&SAX[swz_idx(l15, ks * 4 + kg)]);            \
    bf16x8 a1 = *(const bf16x8*)(&SAX[swz_idx(16 + l15, ks * 4 + kg)]);       \
    bf16x8 b0 = *(const bf16x8*)(&(WB)[swz_idx(colb, ks * 4 + kg)]);          \
    bf16x8 b1 = *(const bf16x8*)(&(WB)[swz_idx(colb + 16, ks * 4 + kg)]);     \
    ACC[0][0] = __builtin_amdgcn_mfma_f32_16x16x32_bf16(a0, b0, ACC[0][0], 0, 0, 0); \
    ACC[0][1] = __builtin_amdgcn_mfma_f32_16x16x32_bf16(a0, b1, ACC[0][1], 0, 0, 0); \
    ACC[1][0] = __builtin_amdgcn_mfma_f32_16x16x32_bf16(a1, b0, ACC[1][0], 0, 0, 0); \
    ACC[1][1] = __builtin_amdgcn_mfma_f32_16x16x32_bf16(a1, b1, ACC[1][1], 0, 0, 0); \
  }

#define STEP(S, NEXTSRC, ACC, SAX)                                            \
  {                                                                           \
    bf16x8 w0, w1, w2, w3, w4, w5, w6, w7;                                    \
    {                                                                         \
      const __bf16* wp = (NEXTSRC) + (long)r0w * 128 + kcw * 8;               \
      w0 = *(const bf16x8*)(wp + 0 * 2048); w1 = *(const bf16x8*)(wp + 1 * 2048); \
      w2 = *(const bf16x8*)(wp + 2 * 2048); w3 = *(const bf16x8*)(wp + 3 * 2048); \
      w4 = *(const bf16x8*)(wp + 4 * 2048); w5 = *(const bf16x8*)(wp + 5 * 2048); \
      w6 = *(const bf16x8*)(wp + 6 * 2048); w7 = *(const bf16x8*)(wp + 7 * 2048); \
    }                                                                         \
    MM(ACC, SAX, sW[(S) & 1])                                                 \
    {                                                                         \
      ushort* wb = sW[((S) + 1) & 1];                                         \
      *(bf16x8*)(&wb[swz_idx(r0w + 0, kcw)])   = w0;                          \
      *(bf16x8*)(&wb[swz_idx(r0w + 16, kcw)])  = w1;                          \
      *(bf16x8*)(&wb[swz_idx(r0w + 32, kcw)])  = w2;                          \
      *(bf16x8*)(&wb[swz_idx(r0w + 48, kcw)])  = w3;                          \
      *(bf16x8*)(&wb[swz_idx(r0w + 64, kcw)])  = w4;                          \
      *(bf16x8*)(&wb[swz_idx(r0w + 80, kcw)])  = w5;                          \
      *(bf16x8*)(&wb[swz_idx(r0w + 96, kcw)])  = w6;                          \
      *(bf16x8*)(&wb[swz_idx(r0w + 112, kcw)]) = w7;                          \
    }                                                                         \
    __syncthreads();                                                          \
  }

  STEP(0, W_hh,          rp,  sA1)
  STEP(1, W_ih + 16384,  rp,  sA2)
  STEP(2, W_hh + 16384,  zp,  sA1)
  STEP(3, W_ih + 32768,  zp,  sA2)
  STEP(4, W_hh + 32768,  inn, sA1)
  STEP(5, Wnext,         hnn, sA2)   // prefetches Wnext into sW[0]
#undef STEP

  // gate math (registers only; hp pre-read)
  float nv[2][2][4];
  #pragma unroll
  for (int ntl = 0; ntl < 2; ++ntl) {
    int col = colb + ntl * 16;
    float bir = b_ih[col], biz = b_ih[col + 128], bin = b_ih[col + 256];
    float bhr = b_hh[col], bhz = b_hh[col + 128], bhn = b_hh[col + 256];
    #pragma unroll
    for (int rt = 0; rt < 2; ++rt)
      #pragma unroll
      for (int j = 0; j < 4; ++j) {
        float rr = 1.f / (1.f + __expf(-(rp[rt][ntl][j] + bir + bhr)));
        float zz = 1.f / (1.f + __expf(-(zp[rt][ntl][j] + biz + bhz)));
        float nn = tanhf(inn[rt][ntl][j] + bin + rr * (hnn[rt][ntl][j] + bhn));
        nv[rt][ntl][j] = fmaxf((1.f - zz) * nn + zz * hp[rt][ntl][j], 0.f);
      }
  }
  // write nxt into LDS: swizzled A-frags (sA1) + linear bounce (sA2)
  #pragma unroll
  for (int rt = 0; rt < 2; ++rt)
    #pragma unroll
    for (int ntl = 0; ntl < 2; ++ntl) {
      int col = colb + ntl * 16;
      #pragma unroll
      for (int j = 0; j < 4; ++j) {
        int row = rt * 16 + kg * 4 + j;
        ushort hb = __builtin_bit_cast(ushort, (__bf16)nv[rt][ntl][j]);
        sA1[swz_idx(row, col >> 3) + (col & 7)] = hb;
        sA2[row * 128 + col] = hb;
      }
    }
  __syncthreads();

  // xr = nxt @ Wnext.T + bnext
  f32x4 acc2[2][2];
  #pragma unroll
  for (int a = 0; a < 2; ++a)
    #pragma unroll
    for (int b = 0; b < 2; ++b) acc2[a][b] = f32x4{0.f, 0.f, 0.f, 0.f};
  MM(acc2, sA1, sW[0])
#undef MM
  #pragma unroll
  for (int ntl = 0; ntl < 2; ++ntl) {
    int col = colb + ntl * 16;
    float bn = bnext[col];
    #pragma unroll
    for (int rt = 0; rt < 2; ++rt)
      #pragma unroll
      for (int j = 0; j < 4; ++j) {
        long r = row0 + rt * 16 + kg * 4 + j;
        if (r < G) xrdst[r * 128 + col] = acc2[rt][ntl][j] + bn;
      }
  }
  if (writeNxt) {
    #pragma unroll
    for (int c0 = 0; c0 < 2; ++c0) {
      int c = tid + c0 * 256;
      int r = c >> 4, chunk = c & 15;
      long gr = row0 + r;
      if (gr < G) {
        bf16x8 v = *(const bf16x8*)(&sA2[r * 128 + chunk * 8]);
        *(bf16x8*)(nxt + gr * 128 + chunk * 8) = v;
      }
    }
  }
}

extern "C" void kernel_launch(void* const* d_in, const int* in_sizes, int n_in,
                              void* d_out, int out_size, void* d_ws, size_t ws_size,
                              hipStream_t stream) {
  const float* x        = (const float*)d_in[0];
  const int*   batch    = (const int*)d_in[1];
  const float* Wl       = (const float*)d_in[2];
  const float* bl       = (const float*)d_in[3];
  const float* Wr       = (const float*)d_in[4];
  const float* br       = (const float*)d_in[5];
  const float* att      = (const float*)d_in[6];
  const float* gat_bias = (const float*)d_in[7];
  const float* W_ih     = (const float*)d_in[8];
  const float* W_hh     = (const float*)d_in[9];
  const float* b_ih     = (const float*)d_in[10];
  const float* b_hh     = (const float*)d_in[11];
  const float* Wfc      = (const float*)d_in[12];
  const float* bfc      = (const float*)d_in[13];
  const int N = in_sizes[1];
  const int G = out_size / G_DIM;
  float* outf = (float*)d_out;

  const int ntiles_big = (N + 63) / 64;
  const long nbands = (long)ntiles_big * 4;

  char* ws = (char*)d_ws;
  size_t off = 0;
  auto alloc = [&](size_t bytes) -> void* {
    void* p = ws + off;
    off = (off + bytes + 255) & ~(size_t)255;
    return p;
  };
  int*    seg      = (int*)alloc(((size_t)G + 1) * sizeof(int));
  float*  poolpart = (float*)alloc((size_t)G * G_DIM * sizeof(float));
  float*  xr       = (float*)alloc((size_t)G * G_DIM * sizeof(float));
  float*  hbuf     = (float*)alloc((size_t)G * G_DIM * sizeof(float));
  __bf16* cb0      = (__bf16*)alloc((size_t)G * G_DIM * sizeof(ushort));
  __bf16* cb1      = (__bf16*)alloc((size_t)G * G_DIM * sizeof(ushort));
  __bf16* wsW      = (__bf16*)alloc((size_t)147456 * sizeof(ushort));
  float*  edgebuf  = (float*)alloc((size_t)nbands * 2 * G_DIM * sizeof(float));
  __bf16* xl       = (__bf16*)alloc((size_t)N * G_DIM * sizeof(ushort));
  (void)ws_size; (void)n_in;

  __bf16* Wlb  = wsW;
  __bf16* Wrb  = wsW + 16384;
  __bf16* Wihb = wsW + 32768;
  __bf16* Whhb = wsW + 81920;
  __bf16* Wfcb = wsW + 131072;

  const int nseg = (N + 255) / 256;
  k_init<<<WCVT_BLOCKS + nseg, 256, 0, stream>>>(Wl, Wr, W_ih, W_hh, Wfc, wsW,
                                                 batch, seg, N, G);

  k_xlgemm<<<768, 256, 0, stream>>>(Wlb, x, bl, batch, xl, poolpart, edgebuf, N, ntiles_big);
  k_poolgemm<<<(G + 63) / 64, 256, 0, stream>>>(seg, edgebuf, poolpart, Wrb, br, xr, cb0, G);

  const int ngru = (G + 31) / 32;
  // t=0
  k_gat<<<(G + 3) / 4, 256, 0, stream>>>(xl, xr, seg, att, gat_bias, hbuf, G);
  k_grufuse<<<ngru, 256, 0, stream>>>(hbuf, cb0, Wihb, Whhb, b_ih, b_hh,
                                      Wrb, br, cb1, xr, G, 1);
  // t=1
  k_gat<<<(G + 3) / 4, 256, 0, stream>>>(xl, xr, seg, att, gat_bias, hbuf, G);
  k_grufuse<<<ngru, 256, 0, stream>>>(hbuf, cb1, Wihb, Whhb, b_ih, b_hh,
                                      Wrb, br, cb0, xr, G, 1);
  // t=2: Wnext = Wfc, write final output directly
  k_gat<<<(G + 3) / 4, 256, 0, stream>>>(xl, xr, seg, att, gat_bias, hbuf, G);
  k_grufuse<<<ngru, 256, 0, stream>>>(hbuf, cb0, Wihb, Whhb, b_ih, b_hh,
                                      Wfcb, bfc, cb1, outf, G, 0);
}